// Round 1
// baseline (594.016 us; speedup 1.0000x reference)
//
#include <hip/hip_runtime.h>

#define D_MODEL 1024
#define D_FFN   4096
#define SEQ     2048
#define NROWS   4096   // B*S

typedef __bf16 bf16x8 __attribute__((ext_vector_type(8)));
typedef float  floatx4 __attribute__((ext_vector_type(4)));

__device__ __forceinline__ unsigned short f2bf(float f) {
  unsigned int u = __float_as_uint(f);
  u += 0x7FFFu + ((u >> 16) & 1u);   // RNE
  return (unsigned short)(u >> 16);
}

// ---------------- fp32 -> bf16 elementwise ----------------
__global__ __launch_bounds__(256) void k_f32_to_bf16(
    const float* __restrict__ in, unsigned short* __restrict__ outp, long n) {
  long i = ((long)blockIdx.x * 256 + threadIdx.x) * 4;
  if (i >= n) return;
  float4 v = *(const float4*)(in + i);
  ushort4 o;
  o.x = f2bf(v.x); o.y = f2bf(v.y); o.z = f2bf(v.z); o.w = f2bf(v.w);
  *(ushort4*)(outp + i) = o;
}

// ------------- transpose+convert: W[R][C] f32 -> WT[C][R] bf16 -------------
__global__ __launch_bounds__(256) void k_transpose_bf16(
    const float* __restrict__ W, unsigned short* __restrict__ WT, int R, int C) {
  __shared__ float tile[32][33];
  int tx = threadIdx.x & 31, ty = threadIdx.x >> 5;
  long bx = (long)blockIdx.x * 32;  // col base in W
  long by = (long)blockIdx.y * 32;  // row base in W
  #pragma unroll
  for (int j = 0; j < 4; j++)
    tile[ty + j * 8][tx] = W[(by + ty + j * 8) * C + bx + tx];
  __syncthreads();
  #pragma unroll
  for (int j = 0; j < 4; j++)
    WT[(bx + ty + j * 8) * R + by + tx] = f2bf(tile[tx][ty + j * 8]);
}

// ---------------- bf16 MFMA GEMM: C[M][N] = A[M][K] @ Bt[N][K]^T + bias ----------------
// flags: bit0 = fp32 output (else bf16), bit1 = relu
#define LDT 40   // 32 + 8 pad: 80B row stride -> 16B aligned, 2-way (free) bank pattern
__global__ __launch_bounds__(256) void k_gemm_bt(
    const unsigned short* __restrict__ A,
    const unsigned short* __restrict__ Bt,
    const float* __restrict__ bias,
    void* __restrict__ Cp,
    int M, int N, int K, int flags) {
  __shared__ unsigned short As[128 * LDT];
  __shared__ unsigned short Bs[128 * LDT];
  int tid = threadIdx.x;
  int lane = tid & 63, wave = tid >> 6;
  int quad = lane >> 4, l16 = lane & 15;
  int wm = (wave & 1) * 64, wn = (wave >> 1) * 64;
  long bm = (long)blockIdx.x * 128;
  long bn = (long)blockIdx.y * 128;

  const floatx4 fz = {0.f, 0.f, 0.f, 0.f};
  floatx4 acc[4][4];
  #pragma unroll
  for (int i = 0; i < 4; i++)
    #pragma unroll
    for (int j = 0; j < 4; j++) acc[i][j] = fz;

  int srow = tid >> 2;            // 0..63 (+64 on 2nd unit): 4 units of 8 elems per 32-col row
  int scol = (tid & 3) * 8;
  const unsigned short* Ag = A + (bm + srow) * (long)K + scol;
  const unsigned short* Bg = Bt + (bn + srow) * (long)K + scol;

  for (int k0 = 0; k0 < K; k0 += 32) {
    #pragma unroll
    for (int j = 0; j < 2; j++) {
      uint4 va = *(const uint4*)(Ag + (long)j * 64 * K + k0);
      *(uint4*)(As + (srow + j * 64) * LDT + scol) = va;
      uint4 vb = *(const uint4*)(Bg + (long)j * 64 * K + k0);
      *(uint4*)(Bs + (srow + j * 64) * LDT + scol) = vb;
    }
    __syncthreads();
    bf16x8 af[4], bfr[4];
    #pragma unroll
    for (int i = 0; i < 4; i++)
      af[i] = *(const bf16x8*)(As + (wm + i * 16 + l16) * LDT + quad * 8);
    #pragma unroll
    for (int j = 0; j < 4; j++)
      bfr[j] = *(const bf16x8*)(Bs + (wn + j * 16 + l16) * LDT + quad * 8);
    #pragma unroll
    for (int i = 0; i < 4; i++)
      #pragma unroll
      for (int j = 0; j < 4; j++)
        acc[i][j] = __builtin_amdgcn_mfma_f32_16x16x32_bf16(af[i], bfr[j], acc[i][j], 0, 0, 0);
    __syncthreads();
  }

  bool f32out = (flags & 1) != 0;
  bool relu   = (flags & 2) != 0;
  #pragma unroll
  for (int j = 0; j < 4; j++) {
    long col = bn + wn + j * 16 + l16;
    float bvv = bias[col];
    #pragma unroll
    for (int i = 0; i < 4; i++) {
      long row = bm + wm + i * 16 + quad * 4;   // C/D layout: row = quad*4+r, col = l16 (m89/m91 verified)
      #pragma unroll
      for (int r = 0; r < 4; r++) {
        float v = acc[i][j][r] + bvv;
        if (relu) v = fmaxf(v, 0.0f);
        if (f32out) ((float*)Cp)[(row + r) * (long)N + col] = v;
        else        ((unsigned short*)Cp)[(row + r) * (long)N + col] = f2bf(v);
      }
    }
  }
}

// ---------------- flash attention (causal), bf16 MFMA ----------------
// Q,K,V: [B*S][1024] bf16 (head h at cols h*64..h*64+63). O: same layout ("bqhd").
#define LKD 72   // 64 + 8 pad: 144B stride, 16B aligned
__global__ __launch_bounds__(256) void k_attn(
    const unsigned short* __restrict__ Q,
    const unsigned short* __restrict__ Kmat,
    const unsigned short* __restrict__ V,
    unsigned short* __restrict__ Omat) {
  __shared__ unsigned short Ks[64 * LKD];
  __shared__ unsigned short Vs[64 * LKD];     // transposed: Vs[d][kv]
  __shared__ unsigned short Ps[4][16 * LKD];  // per-wave P strip
  int tid = threadIdx.x;
  int lane = tid & 63, wave = tid >> 6;
  int quad = lane >> 4, l16 = lane & 15;
  int qt = blockIdx.x, h = blockIdx.y, b = blockIdx.z;
  int q0 = qt * 64;
  long rowbase = (long)b * SEQ;
  int hd0 = h * 64;

  // Q fragments: A-layout A[m=l16][k=quad*8+j], k-chunks of 32 over Hd=64
  bf16x8 qf[2];
  {
    const unsigned short* qp = Q + (rowbase + q0 + wave * 16 + l16) * D_MODEL + hd0 + quad * 8;
    qf[0] = *(const bf16x8*)(qp);
    qf[1] = *(const bf16x8*)(qp + 32);
  }

  const floatx4 fz = {0.f, 0.f, 0.f, 0.f};
  floatx4 ao[4];
  #pragma unroll
  for (int t = 0; t < 4; t++) ao[t] = fz;
  float m_i[4], l_i[4];
  #pragma unroll
  for (int r = 0; r < 4; r++) { m_i[r] = -3.0e38f; l_i[r] = 0.0f; }

  int srow = tid >> 3;          // 64x64 tile staging: 8 units of 8 per row
  int scol = (tid & 7) * 8;
  int qrow = q0 + wave * 16 + quad * 4;

  for (int kv0 = 0; kv0 <= q0; kv0 += 64) {
    #pragma unroll
    for (int j = 0; j < 2; j++) {
      int row = srow + j * 32;
      uint4 kvv = *(const uint4*)(Kmat + (rowbase + kv0 + row) * D_MODEL + hd0 + scol);
      *(uint4*)(Ks + row * LKD + scol) = kvv;
      uint4 vvv = *(const uint4*)(V + (rowbase + kv0 + row) * D_MODEL + hd0 + scol);
      const unsigned short* vvp = (const unsigned short*)&vvv;
      #pragma unroll
      for (int e = 0; e < 8; e++)
        Vs[(scol + e) * LKD + row] = vvp[e];   // transpose scatter
    }
    __syncthreads();

    // S = Q @ K^T  (B-frag: B[k=d][n=kv] = K[kv][d] read contiguous from Ks rows)
    floatx4 sacc[4];
    #pragma unroll
    for (int t = 0; t < 4; t++) {
      sacc[t] = fz;
      bf16x8 kf0 = *(const bf16x8*)(Ks + (t * 16 + l16) * LKD + quad * 8);
      bf16x8 kf1 = *(const bf16x8*)(Ks + (t * 16 + l16) * LKD + 32 + quad * 8);
      sacc[t] = __builtin_amdgcn_mfma_f32_16x16x32_bf16(qf[0], kf0, sacc[t], 0, 0, 0);
      sacc[t] = __builtin_amdgcn_mfma_f32_16x16x32_bf16(qf[1], kf1, sacc[t], 0, 0, 0);
    }

    // scale + causal mask + row max (rows live on 16-lane groups)
    float mt[4];
    #pragma unroll
    for (int r = 0; r < 4; r++) mt[r] = -3.0e38f;
    #pragma unroll
    for (int t = 0; t < 4; t++) {
      int kvc = kv0 + t * 16 + l16;
      #pragma unroll
      for (int r = 0; r < 4; r++) {
        float s = sacc[t][r] * 0.125f;
        if (kvc > qrow + r) s = -3.0e38f;
        sacc[t][r] = s;
        mt[r] = fmaxf(mt[r], s);
      }
    }
    for (int o = 8; o >= 1; o >>= 1) {
      #pragma unroll
      for (int r = 0; r < 4; r++) mt[r] = fmaxf(mt[r], __shfl_xor(mt[r], o, 64));
    }
    float alpha[4], rs[4];
    #pragma unroll
    for (int r = 0; r < 4; r++) {
      float mn = fmaxf(m_i[r], mt[r]);
      alpha[r] = __expf(m_i[r] - mn);
      m_i[r] = mn;
      rs[r] = 0.0f;
    }
    #pragma unroll
    for (int t = 0; t < 4; t++)
      #pragma unroll
      for (int r = 0; r < 4; r++) {
        float p = __expf(sacc[t][r] - m_i[r]);
        sacc[t][r] = p;
        rs[r] += p;
      }
    for (int o = 8; o >= 1; o >>= 1) {
      #pragma unroll
      for (int r = 0; r < 4; r++) rs[r] += __shfl_xor(rs[r], o, 64);
    }
    #pragma unroll
    for (int r = 0; r < 4; r++) l_i[r] = l_i[r] * alpha[r] + rs[r];
    #pragma unroll
    for (int t = 0; t < 4; t++)
      #pragma unroll
      for (int r = 0; r < 4; r++) ao[t][r] *= alpha[r];

    // P: C-layout -> A-layout via per-wave LDS round trip (m120 pattern)
    unsigned short* pw = &Ps[wave][0];
    #pragma unroll
    for (int t = 0; t < 4; t++)
      #pragma unroll
      for (int r = 0; r < 4; r++)
        pw[(quad * 4 + r) * LKD + t * 16 + l16] = f2bf(sacc[t][r]);
    __asm__ volatile("s_waitcnt lgkmcnt(0)" ::: "memory");  // same-wave write->read ordering
    bf16x8 pf0 = *(const bf16x8*)(pw + l16 * LKD + quad * 8);
    bf16x8 pf1 = *(const bf16x8*)(pw + l16 * LKD + 32 + quad * 8);

    // O += P @ V  (B-frag: B[k=kv][n=d] = Vs[d][kv] contiguous)
    #pragma unroll
    for (int t = 0; t < 4; t++) {
      bf16x8 vf0 = *(const bf16x8*)(Vs + (t * 16 + l16) * LKD + quad * 8);
      bf16x8 vf1 = *(const bf16x8*)(Vs + (t * 16 + l16) * LKD + 32 + quad * 8);
      ao[t] = __builtin_amdgcn_mfma_f32_16x16x32_bf16(pf0, vf0, ao[t], 0, 0, 0);
      ao[t] = __builtin_amdgcn_mfma_f32_16x16x32_bf16(pf1, vf1, ao[t], 0, 0, 0);
    }
    __syncthreads();
  }

  float inv[4];
  #pragma unroll
  for (int r = 0; r < 4; r++) inv[r] = 1.0f / l_i[r];
  #pragma unroll
  for (int t = 0; t < 4; t++)
    #pragma unroll
    for (int r = 0; r < 4; r++)
      Omat[(rowbase + qrow + r) * D_MODEL + hd0 + t * 16 + l16] = f2bf(ao[t][r] * inv[r]);
}

// ---------------- fused residual add + layernorm ----------------
__global__ __launch_bounds__(256) void k_add_ln(
    const float* __restrict__ A, const float* __restrict__ Rv,
    const float* __restrict__ g, const float* __restrict__ be,
    float* __restrict__ Y, unsigned short* __restrict__ Ybf) {
  __shared__ float sb[4], ssb[4];
  int tid = threadIdx.x;
  long base = (long)blockIdx.x * D_MODEL + tid * 4;
  float4 a = *(const float4*)(A + base);
  float4 r = *(const float4*)(Rv + base);
  float v0 = a.x + r.x, v1 = a.y + r.y, v2 = a.z + r.z, v3 = a.w + r.w;
  float s  = v0 + v1 + v2 + v3;
  float ss = v0 * v0 + v1 * v1 + v2 * v2 + v3 * v3;
  for (int o = 32; o >= 1; o >>= 1) {
    s  += __shfl_xor(s, o, 64);
    ss += __shfl_xor(ss, o, 64);
  }
  int wave = tid >> 6;
  if ((tid & 63) == 0) { sb[wave] = s; ssb[wave] = ss; }
  __syncthreads();
  s  = sb[0] + sb[1] + sb[2] + sb[3];
  ss = ssb[0] + ssb[1] + ssb[2] + ssb[3];
  float mu  = s * (1.0f / 1024.0f);
  float var = ss * (1.0f / 1024.0f) - mu * mu;
  float rstd = rsqrtf(var + 1e-6f);
  float4 gv  = *(const float4*)(g + tid * 4);
  float4 bev = *(const float4*)(be + tid * 4);
  float o0 = (v0 - mu) * rstd * gv.x + bev.x;
  float o1 = (v1 - mu) * rstd * gv.y + bev.y;
  float o2 = (v2 - mu) * rstd * gv.z + bev.z;
  float o3 = (v3 - mu) * rstd * gv.w + bev.w;
  if (Y) {
    float4 ov = make_float4(o0, o1, o2, o3);
    *(float4*)(Y + base) = ov;
  }
  if (Ybf) {
    ushort4 u;
    u.x = f2bf(o0); u.y = f2bf(o1); u.z = f2bf(o2); u.w = f2bf(o3);
    *(ushort4*)(Ybf + base) = u;
  }
}

extern "C" void kernel_launch(void* const* d_in, const int* in_sizes, int n_in,
                              void* d_out, int out_size, void* d_ws, size_t ws_size,
                              hipStream_t stream) {
  (void)in_sizes; (void)n_in; (void)out_size; (void)ws_size;
  const float* x   = (const float*)d_in[0];
  const float* Wq  = (const float*)d_in[1];
  const float* bq  = (const float*)d_in[2];
  const float* Wk  = (const float*)d_in[3];
  const float* bk  = (const float*)d_in[4];
  const float* Wv  = (const float*)d_in[5];
  const float* bv  = (const float*)d_in[6];
  const float* Wo  = (const float*)d_in[7];
  const float* bo  = (const float*)d_in[8];
  const float* g1  = (const float*)d_in[9];
  const float* b1  = (const float*)d_in[10];
  const float* Wup = (const float*)d_in[11];
  const float* bup = (const float*)d_in[12];
  const float* Wdn = (const float*)d_in[13];
  const float* bdn = (const float*)d_in[14];
  const float* g2  = (const float*)d_in[15];
  const float* b2  = (const float*)d_in[16];
  float* out = (float*)d_out;

  char* ws = (char*)d_ws;
  size_t off = 0;
  auto alloc = [&](size_t bytes) {
    char* p = ws + off;
    off = (off + bytes + 255) & ~(size_t)255;
    return p;
  };
  unsigned short* x_bf   = (unsigned short*)alloc((size_t)NROWS * D_MODEL * 2);
  unsigned short* WqT    = (unsigned short*)alloc((size_t)D_MODEL * D_MODEL * 2);
  unsigned short* WkT    = (unsigned short*)alloc((size_t)D_MODEL * D_MODEL * 2);
  unsigned short* WvT    = (unsigned short*)alloc((size_t)D_MODEL * D_MODEL * 2);
  unsigned short* WoT    = (unsigned short*)alloc((size_t)D_MODEL * D_MODEL * 2);
  unsigned short* WupT   = (unsigned short*)alloc((size_t)D_FFN * D_MODEL * 2);
  unsigned short* WdnT   = (unsigned short*)alloc((size_t)D_MODEL * D_FFN * 2);
  unsigned short* q_bf   = (unsigned short*)alloc((size_t)NROWS * D_MODEL * 2);
  unsigned short* k_bf   = (unsigned short*)alloc((size_t)NROWS * D_MODEL * 2);
  unsigned short* v_bf   = (unsigned short*)alloc((size_t)NROWS * D_MODEL * 2);
  unsigned short* mid_bf = (unsigned short*)alloc((size_t)NROWS * D_MODEL * 2);
  float*          x1f    = (float*)alloc((size_t)NROWS * D_MODEL * 4);
  unsigned short* x1bf   = (unsigned short*)alloc((size_t)NROWS * D_MODEL * 2);
  float*          projdn = (float*)alloc((size_t)NROWS * D_MODEL * 4);  // shared: attn-proj, then ffn-down
  unsigned short* h_bf   = (unsigned short*)alloc((size_t)NROWS * D_FFN * 2);

  k_f32_to_bf16<<<4096, 256, 0, stream>>>(x, x_bf, (long)NROWS * D_MODEL);
  k_transpose_bf16<<<dim3(32, 32), 256, 0, stream>>>(Wq, WqT, D_MODEL, D_MODEL);
  k_transpose_bf16<<<dim3(32, 32), 256, 0, stream>>>(Wk, WkT, D_MODEL, D_MODEL);
  k_transpose_bf16<<<dim3(32, 32), 256, 0, stream>>>(Wv, WvT, D_MODEL, D_MODEL);
  k_transpose_bf16<<<dim3(32, 32), 256, 0, stream>>>(Wo, WoT, D_MODEL, D_MODEL);
  k_transpose_bf16<<<dim3(128, 32), 256, 0, stream>>>(Wup, WupT, D_MODEL, D_FFN);
  k_transpose_bf16<<<dim3(32, 128), 256, 0, stream>>>(Wdn, WdnT, D_FFN, D_MODEL);

  k_gemm_bt<<<dim3(32, 8), 256, 0, stream>>>(x_bf, WqT, bq, q_bf, NROWS, D_MODEL, D_MODEL, 0);
  k_gemm_bt<<<dim3(32, 8), 256, 0, stream>>>(x_bf, WkT, bk, k_bf, NROWS, D_MODEL, D_MODEL, 0);
  k_gemm_bt<<<dim3(32, 8), 256, 0, stream>>>(x_bf, WvT, bv, v_bf, NROWS, D_MODEL, D_MODEL, 0);

  k_attn<<<dim3(32, 16, 2), 256, 0, stream>>>(q_bf, k_bf, v_bf, mid_bf);

  k_gemm_bt<<<dim3(32, 8), 256, 0, stream>>>(mid_bf, WoT, bo, projdn, NROWS, D_MODEL, D_MODEL, 1);
  k_add_ln<<<4096, 256, 0, stream>>>(x, projdn, g1, b1, x1f, x1bf);

  k_gemm_bt<<<dim3(32, 32), 256, 0, stream>>>(x1bf, WupT, bup, h_bf, NROWS, D_FFN, D_MODEL, 2);
  k_gemm_bt<<<dim3(32, 8), 256, 0, stream>>>(h_bf, WdnT, bdn, projdn, NROWS, D_MODEL, D_FFN, 1);
  k_add_ln<<<4096, 256, 0, stream>>>(x1f, projdn, g2, b2, out, nullptr);
}

// Round 2
// 508.225 us; speedup vs baseline: 1.1688x; 1.1688x over previous
//
#include <hip/hip_runtime.h>

#define D_MODEL 1024
#define D_FFN   4096
#define SEQ     2048
#define NROWS   4096   // B*S
#define QKV_LD  3072

typedef __bf16 bf16x8 __attribute__((ext_vector_type(8)));
typedef float  floatx4 __attribute__((ext_vector_type(4)));

__device__ __forceinline__ unsigned short f2bf(float f) {
  unsigned int u = __float_as_uint(f);
  u += 0x7FFFu + ((u >> 16) & 1u);   // RNE
  return (unsigned short)(u >> 16);
}

// async global->LDS, 16B per lane. lds ptr must be wave-uniform; lane i lands at +i*16B.
__device__ __forceinline__ void async16(const unsigned short* g, unsigned short* l) {
  __builtin_amdgcn_global_load_lds(
      (const __attribute__((address_space(1))) unsigned int*)g,
      (__attribute__((address_space(3))) unsigned int*)l, 16, 0, 0);
}

// ---------------- fp32 -> bf16 elementwise ----------------
__global__ __launch_bounds__(256) void k_f32_to_bf16(
    const float* __restrict__ in, unsigned short* __restrict__ outp, long n) {
  long i = ((long)blockIdx.x * 256 + threadIdx.x) * 4;
  if (i >= n) return;
  float4 v = *(const float4*)(in + i);
  ushort4 o;
  o.x = f2bf(v.x); o.y = f2bf(v.y); o.z = f2bf(v.z); o.w = f2bf(v.w);
  *(ushort4*)(outp + i) = o;
}

// ------------- transpose+convert: W[R][C] f32 -> WT[C][R] bf16 -------------
__global__ __launch_bounds__(256) void k_transpose_bf16(
    const float* __restrict__ W, unsigned short* __restrict__ WT, int R, int C) {
  __shared__ float tile[32][33];
  int tx = threadIdx.x & 31, ty = threadIdx.x >> 5;
  long bx = (long)blockIdx.x * 32;  // col base in W
  long by = (long)blockIdx.y * 32;  // row base in W
  #pragma unroll
  for (int j = 0; j < 4; j++)
    tile[ty + j * 8][tx] = W[(by + ty + j * 8) * C + bx + tx];
  __syncthreads();
  #pragma unroll
  for (int j = 0; j < 4; j++)
    WT[(bx + ty + j * 8) * R + by + tx] = f2bf(tile[tx][ty + j * 8]);
}

// ------------- V^T: QKV[:, 2048+d] -> Vt[d][row]  (bf16) -------------
__global__ __launch_bounds__(256) void k_transpose_v(
    const unsigned short* __restrict__ QKV, unsigned short* __restrict__ Vt) {
  __shared__ unsigned short tile[64][72];
  int r0 = blockIdx.x * 64;   // seq-row base
  int c0 = blockIdx.y * 64;   // d base
  int tx = threadIdx.x & 15, ty = threadIdx.x >> 4;
  #pragma unroll
  for (int j = 0; j < 4; j++) {
    int r = ty + j * 16;
    *(ushort4*)&tile[r][tx * 4] =
        *(const ushort4*)(QKV + (long)(r0 + r) * QKV_LD + 2048 + c0 + tx * 4);
  }
  __syncthreads();
  #pragma unroll
  for (int j = 0; j < 4; j++) {
    int d = ty + j * 16;
    ushort4 o;
    o.x = tile[tx * 4 + 0][d];
    o.y = tile[tx * 4 + 1][d];
    o.z = tile[tx * 4 + 2][d];
    o.w = tile[tx * 4 + 3][d];
    *(ushort4*)(Vt + (long)(c0 + d) * NROWS + r0 + tx * 4) = o;
  }
}

// ---------------- m97-style bf16 MFMA GEMM ----------------
// C[M][N] = A[M][K] @ Bt[N][K]^T + bias. BN fixed 128. flags: bit0 f32out, bit1 relu.
template <int BM, int MI>
__global__ __launch_bounds__(256) void k_gemm(
    const unsigned short* __restrict__ A,
    const unsigned short* __restrict__ Bt,
    const float* __restrict__ bias,
    void* __restrict__ Cp, int M, int N, int K, int flags) {
  __shared__ unsigned short As[BM * 32];
  __shared__ unsigned short Bs[128 * 32];
  int tid = threadIdx.x, lane = tid & 63, wave = tid >> 6;
  int quad = lane >> 4, l16 = lane & 15;
  int wm = (wave & 1) * (MI * 16), wn = (wave >> 1) * 64;
  long bm = (long)blockIdx.x * BM;
  long bn = (long)blockIdx.y * 128;

  const floatx4 fz = {0.f, 0.f, 0.f, 0.f};
  floatx4 acc[MI][4];
  #pragma unroll
  for (int i = 0; i < MI; i++)
    #pragma unroll
    for (int j = 0; j < 4; j++) acc[i][j] = fz;

  const unsigned short* Ag = A + (bm + wave * 16 + (lane >> 2)) * (long)K + (lane & 3) * 8;
  const unsigned short* Bg = Bt + (bn + wave * 16 + (lane >> 2)) * (long)K + (lane & 3) * 8;
  unsigned short* Asw = As + wave * 16 * 32;   // wave-uniform LDS bases
  unsigned short* Bsw = Bs + wave * 16 * 32;

  for (int k0 = 0; k0 < K; k0 += 32) {
    async16(Ag + k0, Asw);
    if (BM == 128) async16(Ag + (long)64 * K + k0, Asw + 64 * 32);
    async16(Bg + k0, Bsw);
    async16(Bg + (long)64 * K + k0, Bsw + 64 * 32);
    __syncthreads();
    bf16x8 af[MI], bfr[4];
    #pragma unroll
    for (int i = 0; i < MI; i++)
      af[i] = *(const bf16x8*)(As + (wm + i * 16 + l16) * 32 + quad * 8);
    #pragma unroll
    for (int j = 0; j < 4; j++)
      bfr[j] = *(const bf16x8*)(Bs + (wn + j * 16 + l16) * 32 + quad * 8);
    #pragma unroll
    for (int i = 0; i < MI; i++)
      #pragma unroll
      for (int j = 0; j < 4; j++)
        acc[i][j] = __builtin_amdgcn_mfma_f32_16x16x32_bf16(af[i], bfr[j], acc[i][j], 0, 0, 0);
    __syncthreads();
  }

  bool f32out = (flags & 1) != 0;
  bool relu   = (flags & 2) != 0;
  #pragma unroll
  for (int j = 0; j < 4; j++) {
    long col = bn + wn + j * 16 + l16;
    float bvv = bias[col];
    #pragma unroll
    for (int i = 0; i < MI; i++) {
      long row = bm + wm + i * 16 + quad * 4;
      #pragma unroll
      for (int r = 0; r < 4; r++) {
        float v = acc[i][j][r] + bvv;
        if (relu) v = fmaxf(v, 0.0f);
        if (f32out) ((float*)Cp)[(row + r) * (long)N + col] = v;
        else        ((unsigned short*)Cp)[(row + r) * (long)N + col] = f2bf(v);
      }
    }
  }
}

// ---------------- flash attention (causal), barrier-free ----------------
// QKV: [4096][3072] bf16 (Q at col h*64, K at 1024+h*64). Vt: [1024][4096] bf16.
// Each wave owns a 16-row q strip; K/V fragments direct from global (L1/L2-cached).
#define PLD 72   // P strip row stride (u16): 144B = 16B-aligned; writes 2-way (free)
__global__ __launch_bounds__(256) void k_attn(
    const unsigned short* __restrict__ QKV,
    const unsigned short* __restrict__ Vt,
    unsigned short* __restrict__ Omat) {
  __shared__ unsigned short Ps[4][16 * PLD];
  int tid = threadIdx.x;
  int lane = tid & 63, wave = tid >> 6;
  int quad = lane >> 4, l16 = lane & 15;
  int z = blockIdx.x;
  int qt = 31 - (z >> 5);          // big tiles dispatched first (load balance)
  int bh = z & 31;
  int b = bh >> 4, h = bh & 15;
  long rowbase = (long)b * SEQ;
  int hd0 = h * 64;
  int q0w = qt * 64 + wave * 16;   // wave's strip
  int qrow = q0w + quad * 4;       // this lane's C-layout row base

  unsigned short* pw = &Ps[wave][0];

  bf16x8 qf0, qf1;
  {
    const unsigned short* qp = QKV + (rowbase + q0w + l16) * (long)QKV_LD + hd0 + quad * 8;
    qf0 = *(const bf16x8*)(qp);
    qf1 = *(const bf16x8*)(qp + 32);
  }

  const floatx4 fz = {0.f, 0.f, 0.f, 0.f};
  floatx4 ao[4];
  #pragma unroll
  for (int t = 0; t < 4; t++) ao[t] = fz;
  float m_i[4], l_i[4];
  #pragma unroll
  for (int r = 0; r < 4; r++) { m_i[r] = -3.0e38f; l_i[r] = 0.0f; }

  for (int kv0 = 0; kv0 <= qt * 64; kv0 += 64) {
    // S = Q @ K^T ; K B-frag direct from global rows (k=d contiguous)
    const unsigned short* kp =
        QKV + (rowbase + kv0 + l16) * (long)QKV_LD + 1024 + hd0 + quad * 8;
    floatx4 sacc[4];
    #pragma unroll
    for (int t = 0; t < 4; t++) {
      bf16x8 kf0 = *(const bf16x8*)(kp + (long)t * 16 * QKV_LD);
      bf16x8 kf1 = *(const bf16x8*)(kp + (long)t * 16 * QKV_LD + 32);
      sacc[t] = __builtin_amdgcn_mfma_f32_16x16x32_bf16(qf0, kf0, fz, 0, 0, 0);
      sacc[t] = __builtin_amdgcn_mfma_f32_16x16x32_bf16(qf1, kf1, sacc[t], 0, 0, 0);
    }

    // scale + causal mask + running softmax
    float mt[4];
    #pragma unroll
    for (int r = 0; r < 4; r++) mt[r] = -3.0e38f;
    #pragma unroll
    for (int t = 0; t < 4; t++) {
      int kvc = kv0 + t * 16 + l16;
      #pragma unroll
      for (int r = 0; r < 4; r++) {
        float s = sacc[t][r] * 0.125f;
        if (kvc > qrow + r) s = -3.0e38f;
        sacc[t][r] = s;
        mt[r] = fmaxf(mt[r], s);
      }
    }
    #pragma unroll
    for (int o = 8; o >= 1; o >>= 1) {
      #pragma unroll
      for (int r = 0; r < 4; r++) mt[r] = fmaxf(mt[r], __shfl_xor(mt[r], o, 64));
    }
    float alpha[4], rs[4];
    #pragma unroll
    for (int r = 0; r < 4; r++) {
      float mn = fmaxf(m_i[r], mt[r]);
      alpha[r] = __expf(m_i[r] - mn);
      m_i[r] = mn;
      rs[r] = 0.0f;
    }
    #pragma unroll
    for (int t = 0; t < 4; t++)
      #pragma unroll
      for (int r = 0; r < 4; r++) {
        float p = __expf(sacc[t][r] - m_i[r]);
        sacc[t][r] = p;
        rs[r] += p;
      }
    #pragma unroll
    for (int o = 8; o >= 1; o >>= 1) {
      #pragma unroll
      for (int r = 0; r < 4; r++) rs[r] += __shfl_xor(rs[r], o, 64);
    }
    #pragma unroll
    for (int r = 0; r < 4; r++) l_i[r] = l_i[r] * alpha[r] + rs[r];
    #pragma unroll
    for (int t = 0; t < 4; t++)
      #pragma unroll
      for (int r = 0; r < 4; r++) ao[t][r] *= alpha[r];

    // P: C-layout -> A-layout via per-wave LDS strip (no barrier needed)
    #pragma unroll
    for (int t = 0; t < 4; t++)
      #pragma unroll
      for (int r = 0; r < 4; r++)
        pw[(quad * 4 + r) * PLD + t * 16 + l16] = f2bf(sacc[t][r]);
    __asm__ volatile("s_waitcnt lgkmcnt(0)" ::: "memory");
    bf16x8 pf0 = *(const bf16x8*)(pw + l16 * PLD + quad * 8);
    bf16x8 pf1 = *(const bf16x8*)(pw + l16 * PLD + 32 + quad * 8);

    // O += P @ V ; Vt B-frag direct from global rows (k=kv contiguous)
    const unsigned short* vp = Vt + (long)(hd0 + l16) * NROWS + rowbase + kv0 + quad * 8;
    #pragma unroll
    for (int t = 0; t < 4; t++) {
      bf16x8 vf0 = *(const bf16x8*)(vp + (long)t * 16 * NROWS);
      bf16x8 vf1 = *(const bf16x8*)(vp + (long)t * 16 * NROWS + 32);
      ao[t] = __builtin_amdgcn_mfma_f32_16x16x32_bf16(pf0, vf0, ao[t], 0, 0, 0);
      ao[t] = __builtin_amdgcn_mfma_f32_16x16x32_bf16(pf1, vf1, ao[t], 0, 0, 0);
    }
  }

  float inv[4];
  #pragma unroll
  for (int r = 0; r < 4; r++) inv[r] = 1.0f / l_i[r];
  #pragma unroll
  for (int t = 0; t < 4; t++)
    #pragma unroll
    for (int r = 0; r < 4; r++)
      Omat[(rowbase + qrow + r) * (long)D_MODEL + hd0 + t * 16 + l16] =
          f2bf(ao[t][r] * inv[r]);
}

// ---------------- fused residual add + layernorm ----------------
__global__ __launch_bounds__(256) void k_add_ln(
    const float* __restrict__ A, const float* __restrict__ Rv,
    const float* __restrict__ g, const float* __restrict__ be,
    float* __restrict__ Y, unsigned short* __restrict__ Ybf) {
  __shared__ float sb[4], ssb[4];
  int tid = threadIdx.x;
  long base = (long)blockIdx.x * D_MODEL + tid * 4;
  float4 a = *(const float4*)(A + base);
  float4 r = *(const float4*)(Rv + base);
  float v0 = a.x + r.x, v1 = a.y + r.y, v2 = a.z + r.z, v3 = a.w + r.w;
  float s  = v0 + v1 + v2 + v3;
  float ss = v0 * v0 + v1 * v1 + v2 * v2 + v3 * v3;
  #pragma unroll
  for (int o = 32; o >= 1; o >>= 1) {
    s  += __shfl_xor(s, o, 64);
    ss += __shfl_xor(ss, o, 64);
  }
  int wave = tid >> 6;
  if ((tid & 63) == 0) { sb[wave] = s; ssb[wave] = ss; }
  __syncthreads();
  s  = sb[0] + sb[1] + sb[2] + sb[3];
  ss = ssb[0] + ssb[1] + ssb[2] + ssb[3];
  float mu  = s * (1.0f / 1024.0f);
  float var = ss * (1.0f / 1024.0f) - mu * mu;
  float rstd = rsqrtf(var + 1e-6f);
  float4 gv  = *(const float4*)(g + tid * 4);
  float4 bev = *(const float4*)(be + tid * 4);
  float o0 = (v0 - mu) * rstd * gv.x + bev.x;
  float o1 = (v1 - mu) * rstd * gv.y + bev.y;
  float o2 = (v2 - mu) * rstd * gv.z + bev.z;
  float o3 = (v3 - mu) * rstd * gv.w + bev.w;
  if (Y) *(float4*)(Y + base) = make_float4(o0, o1, o2, o3);
  if (Ybf) {
    ushort4 u;
    u.x = f2bf(o0); u.y = f2bf(o1); u.z = f2bf(o2); u.w = f2bf(o3);
    *(ushort4*)(Ybf + base) = u;
  }
}

extern "C" void kernel_launch(void* const* d_in, const int* in_sizes, int n_in,
                              void* d_out, int out_size, void* d_ws, size_t ws_size,
                              hipStream_t stream) {
  (void)in_sizes; (void)n_in; (void)out_size; (void)ws_size;
  const float* x   = (const float*)d_in[0];
  const float* Wq  = (const float*)d_in[1];
  const float* bq  = (const float*)d_in[2];
  const float* Wk  = (const float*)d_in[3];
  const float* bk  = (const float*)d_in[4];
  const float* Wv  = (const float*)d_in[5];
  const float* bv  = (const float*)d_in[6];
  const float* Wo  = (const float*)d_in[7];
  const float* bo  = (const float*)d_in[8];
  const float* g1  = (const float*)d_in[9];
  const float* b1  = (const float*)d_in[10];
  const float* Wup = (const float*)d_in[11];
  const float* bup = (const float*)d_in[12];
  const float* Wdn = (const float*)d_in[13];
  const float* bdn = (const float*)d_in[14];
  const float* g2  = (const float*)d_in[15];
  const float* b2  = (const float*)d_in[16];
  float* out = (float*)d_out;

  char* ws = (char*)d_ws;
  size_t off = 0;
  auto alloc = [&](size_t bytes) {
    char* p = ws + off;
    off = (off + bytes + 255) & ~(size_t)255;
    return p;
  };
  unsigned short* x_bf   = (unsigned short*)alloc((size_t)NROWS * D_MODEL * 2);
  unsigned short* WqkvT  = (unsigned short*)alloc((size_t)QKV_LD * D_MODEL * 2);
  unsigned short* WoT    = (unsigned short*)alloc((size_t)D_MODEL * D_MODEL * 2);
  unsigned short* WupT   = (unsigned short*)alloc((size_t)D_FFN * D_MODEL * 2);
  unsigned short* WdnT   = (unsigned short*)alloc((size_t)D_MODEL * D_FFN * 2);
  float*          bqkv   = (float*)alloc((size_t)QKV_LD * 4);
  unsigned short* qkv_bf = (unsigned short*)alloc((size_t)NROWS * QKV_LD * 2);
  unsigned short* Vt     = (unsigned short*)alloc((size_t)D_MODEL * NROWS * 2);
  unsigned short* mid_bf = (unsigned short*)alloc((size_t)NROWS * D_MODEL * 2);
  float*          x1f    = (float*)alloc((size_t)NROWS * D_MODEL * 4);
  unsigned short* x1bf   = (unsigned short*)alloc((size_t)NROWS * D_MODEL * 2);
  float*          projdn = (float*)alloc((size_t)NROWS * D_MODEL * 4);
  unsigned short* h_bf   = (unsigned short*)alloc((size_t)NROWS * D_FFN * 2);

  k_f32_to_bf16<<<4096, 256, 0, stream>>>(x, x_bf, (long)NROWS * D_MODEL);
  // Wqkv^T concat: rows 0..1023 = Wq^T, 1024..2047 = Wk^T, 2048..3071 = Wv^T
  k_transpose_bf16<<<dim3(32, 32), 256, 0, stream>>>(Wq, WqkvT, D_MODEL, D_MODEL);
  k_transpose_bf16<<<dim3(32, 32), 256, 0, stream>>>(Wk, WqkvT + 1024 * 1024, D_MODEL, D_MODEL);
  k_transpose_bf16<<<dim3(32, 32), 256, 0, stream>>>(Wv, WqkvT + 2048 * 1024, D_MODEL, D_MODEL);
  k_transpose_bf16<<<dim3(32, 32), 256, 0, stream>>>(Wo, WoT, D_MODEL, D_MODEL);
  k_transpose_bf16<<<dim3(128, 32), 256, 0, stream>>>(Wup, WupT, D_MODEL, D_FFN);
  k_transpose_bf16<<<dim3(32, 128), 256, 0, stream>>>(Wdn, WdnT, D_FFN, D_MODEL);
  hipMemcpyAsync(bqkv,        bq, 1024 * 4, hipMemcpyDeviceToDevice, stream);
  hipMemcpyAsync(bqkv + 1024, bk, 1024 * 4, hipMemcpyDeviceToDevice, stream);
  hipMemcpyAsync(bqkv + 2048, bv, 1024 * 4, hipMemcpyDeviceToDevice, stream);

  // QKV projection (merged): [4096][3072]
  k_gemm<128, 4><<<dim3(32, 24), 256, 0, stream>>>(x_bf, WqkvT, bqkv, qkv_bf,
                                                   NROWS, QKV_LD, D_MODEL, 0);
  k_transpose_v<<<dim3(64, 16), 256, 0, stream>>>(qkv_bf, Vt);

  k_attn<<<1024, 256, 0, stream>>>(qkv_bf, Vt, mid_bf);

  k_gemm<64, 2><<<dim3(64, 8), 256, 0, stream>>>(mid_bf, WoT, bo, projdn,
                                                 NROWS, D_MODEL, D_MODEL, 1);
  k_add_ln<<<4096, 256, 0, stream>>>(x, projdn, g1, b1, x1f, x1bf);

  k_gemm<128, 4><<<dim3(32, 32), 256, 0, stream>>>(x1bf, WupT, bup, h_bf,
                                                   NROWS, D_FFN, D_MODEL, 2);
  k_gemm<64, 2><<<dim3(64, 8), 256, 0, stream>>>(h_bf, WdnT, bdn, projdn,
                                                 NROWS, D_MODEL, D_FFN, 1);
  k_add_ln<<<4096, 256, 0, stream>>>(x1f, projdn, g2, b2, out, nullptr);
}

// Round 3
// 504.124 us; speedup vs baseline: 1.1783x; 1.0081x over previous
//
#include <hip/hip_runtime.h>

#define D_MODEL 1024
#define D_FFN   4096
#define SEQ     2048
#define NROWS   4096   // B*S
#define QKV_LD  3072

typedef __bf16 bf16x8 __attribute__((ext_vector_type(8)));
typedef float  floatx4 __attribute__((ext_vector_type(4)));

__device__ __forceinline__ unsigned short f2bf(float f) {
  unsigned int u = __float_as_uint(f);
  u += 0x7FFFu + ((u >> 16) & 1u);   // RNE
  return (unsigned short)(u >> 16);
}

// async global->LDS, 16B per lane. lds ptr must be wave-uniform; lane i lands at +i*16B.
__device__ __forceinline__ void async16(const unsigned short* g, unsigned short* l) {
  __builtin_amdgcn_global_load_lds(
      (const __attribute__((address_space(1))) unsigned int*)g,
      (__attribute__((address_space(3))) unsigned int*)l, 16, 0, 0);
}

// ---------------- fp32 -> bf16 elementwise ----------------
__global__ __launch_bounds__(256) void k_f32_to_bf16(
    const float* __restrict__ in, unsigned short* __restrict__ outp, long n) {
  long i = ((long)blockIdx.x * 256 + threadIdx.x) * 4;
  if (i >= n) return;
  float4 v = *(const float4*)(in + i);
  ushort4 o;
  o.x = f2bf(v.x); o.y = f2bf(v.y); o.z = f2bf(v.z); o.w = f2bf(v.w);
  *(ushort4*)(outp + i) = o;
}

// ------------- transpose+convert: W[R][C] f32 -> WT[C][R] bf16 -------------
__global__ __launch_bounds__(256) void k_transpose_bf16(
    const float* __restrict__ W, unsigned short* __restrict__ WT, int R, int C) {
  __shared__ float tile[32][33];
  int tx = threadIdx.x & 31, ty = threadIdx.x >> 5;
  long bx = (long)blockIdx.x * 32;  // col base in W
  long by = (long)blockIdx.y * 32;  // row base in W
  #pragma unroll
  for (int j = 0; j < 4; j++)
    tile[ty + j * 8][tx] = W[(by + ty + j * 8) * C + bx + tx];
  __syncthreads();
  #pragma unroll
  for (int j = 0; j < 4; j++)
    WT[(bx + ty + j * 8) * R + by + tx] = f2bf(tile[tx][ty + j * 8]);
}

// ------------- V^T: QKV[:, 2048+d] -> Vt[d][row]  (bf16) -------------
__global__ __launch_bounds__(256) void k_transpose_v(
    const unsigned short* __restrict__ QKV, unsigned short* __restrict__ Vt) {
  __shared__ unsigned short tile[64][72];
  int r0 = blockIdx.x * 64;   // seq-row base
  int c0 = blockIdx.y * 64;   // d base
  int tx = threadIdx.x & 15, ty = threadIdx.x >> 4;
  #pragma unroll
  for (int j = 0; j < 4; j++) {
    int r = ty + j * 16;
    *(ushort4*)&tile[r][tx * 4] =
        *(const ushort4*)(QKV + (long)(r0 + r) * QKV_LD + 2048 + c0 + tx * 4);
  }
  __syncthreads();
  #pragma unroll
  for (int j = 0; j < 4; j++) {
    int d = ty + j * 16;
    ushort4 o;
    o.x = tile[tx * 4 + 0][d];
    o.y = tile[tx * 4 + 1][d];
    o.z = tile[tx * 4 + 2][d];
    o.w = tile[tx * 4 + 3][d];
    *(ushort4*)(Vt + (long)(c0 + d) * NROWS + r0 + tx * 4) = o;
  }
}

// ---------------- m97-style bf16 MFMA GEMM ----------------
// C[M][N] = A[M][K] @ Bt[N][K]^T + bias. BN fixed 128. flags: bit0 f32out, bit1 relu.
template <int BM, int MI>
__global__ __launch_bounds__(256) void k_gemm(
    const unsigned short* __restrict__ A,
    const unsigned short* __restrict__ Bt,
    const float* __restrict__ bias,
    void* __restrict__ Cp, int M, int N, int K, int flags) {
  __shared__ unsigned short As[BM * 32];
  __shared__ unsigned short Bs[128 * 32];
  int tid = threadIdx.x, lane = tid & 63, wave = tid >> 6;
  int quad = lane >> 4, l16 = lane & 15;
  int wm = (wave & 1) * (MI * 16), wn = (wave >> 1) * 64;
  long bm = (long)blockIdx.x * BM;
  long bn = (long)blockIdx.y * 128;

  const floatx4 fz = {0.f, 0.f, 0.f, 0.f};
  floatx4 acc[MI][4];
  #pragma unroll
  for (int i = 0; i < MI; i++)
    #pragma unroll
    for (int j = 0; j < 4; j++) acc[i][j] = fz;

  const unsigned short* Ag = A + (bm + wave * 16 + (lane >> 2)) * (long)K + (lane & 3) * 8;
  const unsigned short* Bg = Bt + (bn + wave * 16 + (lane >> 2)) * (long)K + (lane & 3) * 8;
  unsigned short* Asw = As + wave * 16 * 32;   // wave-uniform LDS bases
  unsigned short* Bsw = Bs + wave * 16 * 32;

  for (int k0 = 0; k0 < K; k0 += 32) {
    async16(Ag + k0, Asw);
    if (BM == 128) async16(Ag + (long)64 * K + k0, Asw + 64 * 32);
    async16(Bg + k0, Bsw);
    async16(Bg + (long)64 * K + k0, Bsw + 64 * 32);
    __syncthreads();
    bf16x8 af[MI], bfr[4];
    #pragma unroll
    for (int i = 0; i < MI; i++)
      af[i] = *(const bf16x8*)(As + (wm + i * 16 + l16) * 32 + quad * 8);
    #pragma unroll
    for (int j = 0; j < 4; j++)
      bfr[j] = *(const bf16x8*)(Bs + (wn + j * 16 + l16) * 32 + quad * 8);
    #pragma unroll
    for (int i = 0; i < MI; i++)
      #pragma unroll
      for (int j = 0; j < 4; j++)
        acc[i][j] = __builtin_amdgcn_mfma_f32_16x16x32_bf16(af[i], bfr[j], acc[i][j], 0, 0, 0);
    __syncthreads();
  }

  bool f32out = (flags & 1) != 0;
  bool relu   = (flags & 2) != 0;
  #pragma unroll
  for (int j = 0; j < 4; j++) {
    long col = bn + wn + j * 16 + l16;
    float bvv = bias[col];
    #pragma unroll
    for (int i = 0; i < MI; i++) {
      long row = bm + wm + i * 16 + quad * 4;
      #pragma unroll
      for (int r = 0; r < 4; r++) {
        float v = acc[i][j][r] + bvv;
        if (relu) v = fmaxf(v, 0.0f);
        if (f32out) ((float*)Cp)[(row + r) * (long)N + col] = v;
        else        ((unsigned short*)Cp)[(row + r) * (long)N + col] = f2bf(v);
      }
    }
  }
}

// ---------------- flash attention (causal), wave-independent ----------------
// QKV: [4096][3072] bf16 (Q at col h*64, K at 1024+h*64). Vt: [1024][4096] bf16.
// 128-thread blocks, 2 independent waves; each wave owns one 16-row q-strip.
// 2048 blocks (8x CU oversubscription) + big-qt-first ordering = dynamic balance.
#define PLD 72   // P strip row stride (u16): 144B = 16B-aligned
__global__ __launch_bounds__(128) void k_attn(
    const unsigned short* __restrict__ QKV,
    const unsigned short* __restrict__ Vt,
    unsigned short* __restrict__ Omat) {
  __shared__ unsigned short Ps[2][16 * PLD];
  int tid = threadIdx.x;
  int lane = tid & 63, wave = tid >> 6;
  int quad = lane >> 4, l16 = lane & 15;
  int z = blockIdx.x;
  int qt = 31 - (z >> 6);          // big q-tiles dispatched first (drain-order balance)
  int rem = z & 63;
  int bh = rem >> 1;               // 0..31
  int half = rem & 1;
  int b = bh >> 4, h = bh & 15;
  long rowbase = (long)b * SEQ;
  int hd0 = h * 64;
  int strip = half * 2 + wave;     // 0..3 within the 64-row q-tile
  int q0w = qt * 64 + strip * 16;  // wave's strip base
  int qrow = q0w + quad * 4;       // this lane's C-layout row base

  unsigned short* pw = &Ps[wave][0];

  bf16x8 qf0, qf1;
  {
    const unsigned short* qp = QKV + (rowbase + q0w + l16) * (long)QKV_LD + hd0 + quad * 8;
    qf0 = *(const bf16x8*)(qp);
    qf1 = *(const bf16x8*)(qp + 32);
  }

  const floatx4 fz = {0.f, 0.f, 0.f, 0.f};
  floatx4 ao[4];
  #pragma unroll
  for (int t = 0; t < 4; t++) ao[t] = fz;
  float m_i[4], l_i[4];
  #pragma unroll
  for (int r = 0; r < 4; r++) { m_i[r] = -3.0e38f; l_i[r] = 0.0f; }

  for (int kv0 = 0; kv0 <= q0w; kv0 += 64) {
    // S = Q @ K^T ; K B-frag direct from global rows (k=d contiguous)
    const unsigned short* kp =
        QKV + (rowbase + kv0 + l16) * (long)QKV_LD + 1024 + hd0 + quad * 8;
    floatx4 sacc[4];
    #pragma unroll
    for (int t = 0; t < 4; t++) {
      bf16x8 kf0 = *(const bf16x8*)(kp + (long)t * 16 * QKV_LD);
      bf16x8 kf1 = *(const bf16x8*)(kp + (long)t * 16 * QKV_LD + 32);
      sacc[t] = __builtin_amdgcn_mfma_f32_16x16x32_bf16(qf0, kf0, fz, 0, 0, 0);
      sacc[t] = __builtin_amdgcn_mfma_f32_16x16x32_bf16(qf1, kf1, sacc[t], 0, 0, 0);
    }

    // scale + causal mask + running softmax
    float mt[4];
    #pragma unroll
    for (int r = 0; r < 4; r++) mt[r] = -3.0e38f;
    #pragma unroll
    for (int t = 0; t < 4; t++) {
      int kvc = kv0 + t * 16 + l16;
      #pragma unroll
      for (int r = 0; r < 4; r++) {
        float s = sacc[t][r] * 0.125f;
        if (kvc > qrow + r) s = -3.0e38f;
        sacc[t][r] = s;
        mt[r] = fmaxf(mt[r], s);
      }
    }
    #pragma unroll
    for (int o = 8; o >= 1; o >>= 1) {
      #pragma unroll
      for (int r = 0; r < 4; r++) mt[r] = fmaxf(mt[r], __shfl_xor(mt[r], o, 64));
    }
    float alpha[4], rs[4];
    #pragma unroll
    for (int r = 0; r < 4; r++) {
      float mn = fmaxf(m_i[r], mt[r]);
      alpha[r] = __expf(m_i[r] - mn);
      m_i[r] = mn;
      rs[r] = 0.0f;
    }
    #pragma unroll
    for (int t = 0; t < 4; t++)
      #pragma unroll
      for (int r = 0; r < 4; r++) {
        float p = __expf(sacc[t][r] - m_i[r]);
        sacc[t][r] = p;
        rs[r] += p;
      }
    #pragma unroll
    for (int o = 8; o >= 1; o >>= 1) {
      #pragma unroll
      for (int r = 0; r < 4; r++) rs[r] += __shfl_xor(rs[r], o, 64);
    }
    #pragma unroll
    for (int r = 0; r < 4; r++) l_i[r] = l_i[r] * alpha[r] + rs[r];
    #pragma unroll
    for (int t = 0; t < 4; t++)
      #pragma unroll
      for (int r = 0; r < 4; r++) ao[t][r] *= alpha[r];

    // P: C-layout -> A-layout via per-wave LDS strip (no barrier needed)
    #pragma unroll
    for (int t = 0; t < 4; t++)
      #pragma unroll
      for (int r = 0; r < 4; r++)
        pw[(quad * 4 + r) * PLD + t * 16 + l16] = f2bf(sacc[t][r]);
    __asm__ volatile("s_waitcnt lgkmcnt(0)" ::: "memory");
    bf16x8 pf0 = *(const bf16x8*)(pw + l16 * PLD + quad * 8);
    bf16x8 pf1 = *(const bf16x8*)(pw + l16 * PLD + 32 + quad * 8);

    // O += P @ V ; Vt B-frag direct from global rows (k=kv contiguous)
    const unsigned short* vp = Vt + (long)(hd0 + l16) * NROWS + rowbase + kv0 + quad * 8;
    #pragma unroll
    for (int t = 0; t < 4; t++) {
      bf16x8 vf0 = *(const bf16x8*)(vp + (long)t * 16 * NROWS);
      bf16x8 vf1 = *(const bf16x8*)(vp + (long)t * 16 * NROWS + 32);
      ao[t] = __builtin_amdgcn_mfma_f32_16x16x32_bf16(pf0, vf0, ao[t], 0, 0, 0);
      ao[t] = __builtin_amdgcn_mfma_f32_16x16x32_bf16(pf1, vf1, ao[t], 0, 0, 0);
    }
  }

  float inv[4];
  #pragma unroll
  for (int r = 0; r < 4; r++) inv[r] = 1.0f / l_i[r];
  #pragma unroll
  for (int t = 0; t < 4; t++)
    #pragma unroll
    for (int r = 0; r < 4; r++)
      Omat[(rowbase + qrow + r) * (long)D_MODEL + hd0 + t * 16 + l16] =
          f2bf(ao[t][r] * inv[r]);
}

// ---------------- fused residual add + layernorm ----------------
__global__ __launch_bounds__(256) void k_add_ln(
    const float* __restrict__ A, const float* __restrict__ Rv,
    const float* __restrict__ g, const float* __restrict__ be,
    float* __restrict__ Y, unsigned short* __restrict__ Ybf) {
  __shared__ float sb[4], ssb[4];
  int tid = threadIdx.x;
  long base = (long)blockIdx.x * D_MODEL + tid * 4;
  float4 a = *(const float4*)(A + base);
  float4 r = *(const float4*)(Rv + base);
  float v0 = a.x + r.x, v1 = a.y + r.y, v2 = a.z + r.z, v3 = a.w + r.w;
  float s  = v0 + v1 + v2 + v3;
  float ss = v0 * v0 + v1 * v1 + v2 * v2 + v3 * v3;
  #pragma unroll
  for (int o = 32; o >= 1; o >>= 1) {
    s  += __shfl_xor(s, o, 64);
    ss += __shfl_xor(ss, o, 64);
  }
  int wave = tid >> 6;
  if ((tid & 63) == 0) { sb[wave] = s; ssb[wave] = ss; }
  __syncthreads();
  s  = sb[0] + sb[1] + sb[2] + sb[3];
  ss = ssb[0] + ssb[1] + ssb[2] + ssb[3];
  float mu  = s * (1.0f / 1024.0f);
  float var = ss * (1.0f / 1024.0f) - mu * mu;
  float rstd = rsqrtf(var + 1e-6f);
  float4 gv  = *(const float4*)(g + tid * 4);
  float4 bev = *(const float4*)(be + tid * 4);
  float o0 = (v0 - mu) * rstd * gv.x + bev.x;
  float o1 = (v1 - mu) * rstd * gv.y + bev.y;
  float o2 = (v2 - mu) * rstd * gv.z + bev.z;
  float o3 = (v3 - mu) * rstd * gv.w + bev.w;
  if (Y) *(float4*)(Y + base) = make_float4(o0, o1, o2, o3);
  if (Ybf) {
    ushort4 u;
    u.x = f2bf(o0); u.y = f2bf(o1); u.z = f2bf(o2); u.w = f2bf(o3);
    *(ushort4*)(Ybf + base) = u;
  }
}

extern "C" void kernel_launch(void* const* d_in, const int* in_sizes, int n_in,
                              void* d_out, int out_size, void* d_ws, size_t ws_size,
                              hipStream_t stream) {
  (void)in_sizes; (void)n_in; (void)out_size; (void)ws_size;
  const float* x   = (const float*)d_in[0];
  const float* Wq  = (const float*)d_in[1];
  const float* bq  = (const float*)d_in[2];
  const float* Wk  = (const float*)d_in[3];
  const float* bk  = (const float*)d_in[4];
  const float* Wv  = (const float*)d_in[5];
  const float* bv  = (const float*)d_in[6];
  const float* Wo  = (const float*)d_in[7];
  const float* bo  = (const float*)d_in[8];
  const float* g1  = (const float*)d_in[9];
  const float* b1  = (const float*)d_in[10];
  const float* Wup = (const float*)d_in[11];
  const float* bup = (const float*)d_in[12];
  const float* Wdn = (const float*)d_in[13];
  const float* bdn = (const float*)d_in[14];
  const float* g2  = (const float*)d_in[15];
  const float* b2  = (const float*)d_in[16];
  float* out = (float*)d_out;

  char* ws = (char*)d_ws;
  size_t off = 0;
  auto alloc = [&](size_t bytes) {
    char* p = ws + off;
    off = (off + bytes + 255) & ~(size_t)255;
    return p;
  };
  unsigned short* x_bf   = (unsigned short*)alloc((size_t)NROWS * D_MODEL * 2);
  unsigned short* WqkvT  = (unsigned short*)alloc((size_t)QKV_LD * D_MODEL * 2);
  unsigned short* WoT    = (unsigned short*)alloc((size_t)D_MODEL * D_MODEL * 2);
  unsigned short* WupT   = (unsigned short*)alloc((size_t)D_FFN * D_MODEL * 2);
  unsigned short* WdnT   = (unsigned short*)alloc((size_t)D_MODEL * D_FFN * 2);
  float*          bqkv   = (float*)alloc((size_t)QKV_LD * 4);
  unsigned short* qkv_bf = (unsigned short*)alloc((size_t)NROWS * QKV_LD * 2);
  unsigned short* Vt     = (unsigned short*)alloc((size_t)D_MODEL * NROWS * 2);
  unsigned short* mid_bf = (unsigned short*)alloc((size_t)NROWS * D_MODEL * 2);
  float*          x1f    = (float*)alloc((size_t)NROWS * D_MODEL * 4);
  unsigned short* x1bf   = (unsigned short*)alloc((size_t)NROWS * D_MODEL * 2);
  float*          projdn = (float*)alloc((size_t)NROWS * D_MODEL * 4);
  unsigned short* h_bf   = (unsigned short*)alloc((size_t)NROWS * D_FFN * 2);

  k_f32_to_bf16<<<4096, 256, 0, stream>>>(x, x_bf, (long)NROWS * D_MODEL);
  // Wqkv^T concat: rows 0..1023 = Wq^T, 1024..2047 = Wk^T, 2048..3071 = Wv^T
  k_transpose_bf16<<<dim3(32, 32), 256, 0, stream>>>(Wq, WqkvT, D_MODEL, D_MODEL);
  k_transpose_bf16<<<dim3(32, 32), 256, 0, stream>>>(Wk, WqkvT + 1024 * 1024, D_MODEL, D_MODEL);
  k_transpose_bf16<<<dim3(32, 32), 256, 0, stream>>>(Wv, WqkvT + 2048 * 1024, D_MODEL, D_MODEL);
  k_transpose_bf16<<<dim3(32, 32), 256, 0, stream>>>(Wo, WoT, D_MODEL, D_MODEL);
  k_transpose_bf16<<<dim3(128, 32), 256, 0, stream>>>(Wup, WupT, D_MODEL, D_FFN);
  k_transpose_bf16<<<dim3(32, 128), 256, 0, stream>>>(Wdn, WdnT, D_FFN, D_MODEL);
  hipMemcpyAsync(bqkv,        bq, 1024 * 4, hipMemcpyDeviceToDevice, stream);
  hipMemcpyAsync(bqkv + 1024, bk, 1024 * 4, hipMemcpyDeviceToDevice, stream);
  hipMemcpyAsync(bqkv + 2048, bv, 1024 * 4, hipMemcpyDeviceToDevice, stream);

  // QKV projection (merged): [4096][3072]
  k_gemm<128, 4><<<dim3(32, 24), 256, 0, stream>>>(x_bf, WqkvT, bqkv, qkv_bf,
                                                   NROWS, QKV_LD, D_MODEL, 0);
  k_transpose_v<<<dim3(64, 16), 256, 0, stream>>>(qkv_bf, Vt);

  k_attn<<<2048, 128, 0, stream>>>(qkv_bf, Vt, mid_bf);

  k_gemm<64, 2><<<dim3(64, 8), 256, 0, stream>>>(mid_bf, WoT, bo, projdn,
                                                 NROWS, D_MODEL, D_MODEL, 1);
  k_add_ln<<<4096, 256, 0, stream>>>(x, projdn, g1, b1, x1f, x1bf);

  k_gemm<128, 4><<<dim3(32, 32), 256, 0, stream>>>(x1bf, WupT, bup, h_bf,
                                                   NROWS, D_FFN, D_MODEL, 2);
  k_gemm<64, 2><<<dim3(64, 8), 256, 0, stream>>>(h_bf, WdnT, bdn, projdn,
                                                 NROWS, D_MODEL, D_FFN, 1);
  k_add_ln<<<4096, 256, 0, stream>>>(x1f, projdn, g2, b2, out, nullptr);
}

// Round 4
// 483.915 us; speedup vs baseline: 1.2275x; 1.0418x over previous
//
#include <hip/hip_runtime.h>

#define D_MODEL 1024
#define D_FFN   4096
#define SEQ     2048
#define NROWS   4096   // B*S
#define QKV_LD  3072

typedef __bf16 bf16x8 __attribute__((ext_vector_type(8)));
typedef float  floatx4 __attribute__((ext_vector_type(4)));

__device__ __forceinline__ unsigned short f2bf(float f) {
  unsigned int u = __float_as_uint(f);
  u += 0x7FFFu + ((u >> 16) & 1u);   // RNE
  return (unsigned short)(u >> 16);
}

// DPP row_ror<N> within 16-lane rows (VALU-speed cross-lane; no LDS pipe)
template <int C>
__device__ __forceinline__ float ror16(float x) {
  return __int_as_float(
      __builtin_amdgcn_mov_dpp(__float_as_int(x), 0x120 | C, 0xf, 0xf, true));
}

// async global->LDS, 16B per lane. lds ptr must be wave-uniform; lane i lands at +i*16B.
__device__ __forceinline__ void async16(const unsigned short* g, unsigned short* l) {
  __builtin_amdgcn_global_load_lds(
      (const __attribute__((address_space(1))) unsigned int*)g,
      (__attribute__((address_space(3))) unsigned int*)l, 16, 0, 0);
}

// ---------------- fp32 -> bf16 elementwise ----------------
__global__ __launch_bounds__(256) void k_f32_to_bf16(
    const float* __restrict__ in, unsigned short* __restrict__ outp, long n) {
  long i = ((long)blockIdx.x * 256 + threadIdx.x) * 4;
  if (i >= n) return;
  float4 v = *(const float4*)(in + i);
  ushort4 o;
  o.x = f2bf(v.x); o.y = f2bf(v.y); o.z = f2bf(v.z); o.w = f2bf(v.w);
  *(ushort4*)(outp + i) = o;
}

// ------------- transpose+convert: W[R][C] f32 -> WT[C][R] bf16 -------------
__global__ __launch_bounds__(256) void k_transpose_bf16(
    const float* __restrict__ W, unsigned short* __restrict__ WT, int R, int C) {
  __shared__ float tile[32][33];
  int tx = threadIdx.x & 31, ty = threadIdx.x >> 5;
  long bx = (long)blockIdx.x * 32;
  long by = (long)blockIdx.y * 32;
  #pragma unroll
  for (int j = 0; j < 4; j++)
    tile[ty + j * 8][tx] = W[(by + ty + j * 8) * C + bx + tx];
  __syncthreads();
  #pragma unroll
  for (int j = 0; j < 4; j++)
    WT[(bx + ty + j * 8) * R + by + tx] = f2bf(tile[tx][ty + j * 8]);
}

// ------------- QKV weight transposes fused (z selects Wq/Wk/Wv) -------------
__global__ __launch_bounds__(256) void k_transpose_qkv(
    const float* __restrict__ Wq, const float* __restrict__ Wk,
    const float* __restrict__ Wv, unsigned short* __restrict__ WT) {
  __shared__ float tile[32][33];
  int z = blockIdx.z;
  const float* W = (z == 0) ? Wq : (z == 1) ? Wk : Wv;
  unsigned short* dst = WT + (size_t)z * D_MODEL * D_MODEL;
  int tx = threadIdx.x & 31, ty = threadIdx.x >> 5;
  long bx = (long)blockIdx.x * 32;
  long by = (long)blockIdx.y * 32;
  #pragma unroll
  for (int j = 0; j < 4; j++)
    tile[ty + j * 8][tx] = W[(by + ty + j * 8) * D_MODEL + bx + tx];
  __syncthreads();
  #pragma unroll
  for (int j = 0; j < 4; j++)
    dst[(bx + ty + j * 8) * D_MODEL + by + tx] = f2bf(tile[tx][ty + j * 8]);
}

__global__ __launch_bounds__(256) void k_pack_bias(
    const float* __restrict__ bq, const float* __restrict__ bk,
    const float* __restrict__ bv, float* __restrict__ dst) {
  int i = blockIdx.x * 256 + threadIdx.x;
  if (i >= 3072) return;
  float v = (i < 1024) ? bq[i] : (i < 2048) ? bk[i - 1024] : bv[i - 2048];
  dst[i] = v;
}

// ------------- V^T: QKV[:, 2048+d] -> Vt[d][row]  (bf16) -------------
__global__ __launch_bounds__(256) void k_transpose_v(
    const unsigned short* __restrict__ QKV, unsigned short* __restrict__ Vt) {
  __shared__ unsigned short tile[64][72];
  int r0 = blockIdx.x * 64;
  int c0 = blockIdx.y * 64;
  int tx = threadIdx.x & 15, ty = threadIdx.x >> 4;
  #pragma unroll
  for (int j = 0; j < 4; j++) {
    int r = ty + j * 16;
    *(ushort4*)&tile[r][tx * 4] =
        *(const ushort4*)(QKV + (long)(r0 + r) * QKV_LD + 2048 + c0 + tx * 4);
  }
  __syncthreads();
  #pragma unroll
  for (int j = 0; j < 4; j++) {
    int d = ty + j * 16;
    ushort4 o;
    o.x = tile[tx * 4 + 0][d];
    o.y = tile[tx * 4 + 1][d];
    o.z = tile[tx * 4 + 2][d];
    o.w = tile[tx * 4 + 3][d];
    *(ushort4*)(Vt + (long)(c0 + d) * NROWS + r0 + tx * 4) = o;
  }
}

// ---------------- m97-style bf16 MFMA GEMM, optional split-K over gridDim.z ----
// C[M][N] = A[M][K] @ Bt[N][K]^T + bias. 128x128 tile. flags: bit0 f32out, bit1 relu.
// gridDim.z>1: each z computes a K-slice into Cp + z*M*N (f32), bias only on z=0.
__global__ __launch_bounds__(256) void k_gemm(
    const unsigned short* __restrict__ A,
    const unsigned short* __restrict__ Bt,
    const float* __restrict__ bias,
    void* __restrict__ Cp, int M, int N, int K, int flags) {
  __shared__ unsigned short As[128 * 32];
  __shared__ unsigned short Bs[128 * 32];
  int tid = threadIdx.x, lane = tid & 63, wave = tid >> 6;
  int quad = lane >> 4, l16 = lane & 15;
  int wm = (wave & 1) * 64, wn = (wave >> 1) * 64;
  long bm = (long)blockIdx.x * 128;
  long bn = (long)blockIdx.y * 128;
  int nz = gridDim.z, z = blockIdx.z;
  int Ks = K / nz;
  long zb = (long)z * Ks;

  const floatx4 fz = {0.f, 0.f, 0.f, 0.f};
  floatx4 acc[4][4];
  #pragma unroll
  for (int i = 0; i < 4; i++)
    #pragma unroll
    for (int j = 0; j < 4; j++) acc[i][j] = fz;

  const unsigned short* Ag = A + (bm + wave * 16 + (lane >> 2)) * (long)K + zb + (lane & 3) * 8;
  const unsigned short* Bg = Bt + (bn + wave * 16 + (lane >> 2)) * (long)K + zb + (lane & 3) * 8;
  unsigned short* Asw = As + wave * 16 * 32;
  unsigned short* Bsw = Bs + wave * 16 * 32;

  for (int k0 = 0; k0 < Ks; k0 += 32) {
    async16(Ag + k0, Asw);
    async16(Ag + (long)64 * K + k0, Asw + 64 * 32);
    async16(Bg + k0, Bsw);
    async16(Bg + (long)64 * K + k0, Bsw + 64 * 32);
    __syncthreads();
    bf16x8 af[4], bfr[4];
    #pragma unroll
    for (int i = 0; i < 4; i++)
      af[i] = *(const bf16x8*)(As + (wm + i * 16 + l16) * 32 + quad * 8);
    #pragma unroll
    for (int j = 0; j < 4; j++)
      bfr[j] = *(const bf16x8*)(Bs + (wn + j * 16 + l16) * 32 + quad * 8);
    #pragma unroll
    for (int i = 0; i < 4; i++)
      #pragma unroll
      for (int j = 0; j < 4; j++)
        acc[i][j] = __builtin_amdgcn_mfma_f32_16x16x32_bf16(af[i], bfr[j], acc[i][j], 0, 0, 0);
    __syncthreads();
  }

  bool f32out = (flags & 1) != 0;
  bool relu   = (flags & 2) != 0;
  float* outf = (float*)Cp + (size_t)z * M * (size_t)N;
  #pragma unroll
  for (int j = 0; j < 4; j++) {
    long col = bn + wn + j * 16 + l16;
    float bvv = (z == 0) ? bias[col] : 0.0f;
    #pragma unroll
    for (int i = 0; i < 4; i++) {
      long row = bm + wm + i * 16 + quad * 4;
      #pragma unroll
      for (int r = 0; r < 4; r++) {
        float v = acc[i][j][r] + bvv;
        if (relu) v = fmaxf(v, 0.0f);
        if (f32out) outf[(row + r) * (long)N + col] = v;
        else        ((unsigned short*)Cp)[(row + r) * (long)N + col] = f2bf(v);
      }
    }
  }
}

// ---------------- flash attention (causal), register-pipelined ----------------
// QKV: [4096][3072] bf16 (Q at col h*64, K at 1024+h*64). Vt: [1024][4096] bf16.
// 128-thread blocks, 2 independent waves; per-wave 16-row q-strip.
// K frags double-buffered in registers (prefetch next tile); V frags loaded
// before the softmax so their latency hides under it; softmax reductions via
// DPP row_ror (VALU) instead of ds_swizzle.
#define PLD 72
__global__ __launch_bounds__(128) void k_attn(
    const unsigned short* __restrict__ QKV,
    const unsigned short* __restrict__ Vt,
    unsigned short* __restrict__ Omat) {
  __shared__ unsigned short Ps[2][16 * PLD];
  int tid = threadIdx.x;
  int lane = tid & 63, wave = tid >> 6;
  int quad = lane >> 4, l16 = lane & 15;
  int z = blockIdx.x;
  int qt = 31 - (z >> 6);          // big q-tiles first
  int rem = z & 63;
  int bh = rem >> 1;
  int half = rem & 1;
  int b = bh >> 4, h = bh & 15;
  long rowbase = (long)b * SEQ;
  int hd0 = h * 64;
  int strip = half * 2 + wave;
  int q0w = qt * 64 + strip * 16;
  int qrow = q0w + quad * 4;

  unsigned short* pw = &Ps[wave][0];

  bf16x8 qf0, qf1;
  {
    const unsigned short* qp = QKV + (rowbase + q0w + l16) * (long)QKV_LD + hd0 + quad * 8;
    qf0 = *(const bf16x8*)(qp);
    qf1 = *(const bf16x8*)(qp + 32);
  }

  const floatx4 fz = {0.f, 0.f, 0.f, 0.f};
  floatx4 ao[4];
  #pragma unroll
  for (int t = 0; t < 4; t++) ao[t] = fz;
  float m_i[4], l_i[4];
  #pragma unroll
  for (int r = 0; r < 4; r++) { m_i[r] = -3.0e38f; l_i[r] = 0.0f; }

  int ntiles = (q0w >> 6) + 1;

  auto loadK = [&](bf16x8 (&dst)[8], int kv0) {
    const unsigned short* kp =
        QKV + (rowbase + kv0 + l16) * (long)QKV_LD + 1024 + hd0 + quad * 8;
    #pragma unroll
    for (int t = 0; t < 4; t++) {
      dst[2 * t]     = *(const bf16x8*)(kp + (long)t * 16 * QKV_LD);
      dst[2 * t + 1] = *(const bf16x8*)(kp + (long)t * 16 * QKV_LD + 32);
    }
  };

  auto step = [&](bf16x8 (&kc)[8], bf16x8 (&kn)[8], int it) {
    int kv0 = it << 6;
    // prefetch next K tile (consumed next iteration)
    if (it + 1 < ntiles) loadK(kn, kv0 + 64);
    // V frags for THIS tile — issued before softmax so latency hides under it
    bf16x8 vf[8];
    {
      const unsigned short* vp =
          Vt + (long)(hd0 + l16) * NROWS + rowbase + kv0 + quad * 8;
      #pragma unroll
      for (int t = 0; t < 4; t++) {
        vf[2 * t]     = *(const bf16x8*)(vp + (long)t * 16 * NROWS);
        vf[2 * t + 1] = *(const bf16x8*)(vp + (long)t * 16 * NROWS + 32);
      }
    }
    // S = Q @ K^T (K frags already in registers)
    floatx4 sacc[4];
    #pragma unroll
    for (int t = 0; t < 4; t++) {
      sacc[t] = __builtin_amdgcn_mfma_f32_16x16x32_bf16(qf0, kc[2 * t], fz, 0, 0, 0);
      sacc[t] = __builtin_amdgcn_mfma_f32_16x16x32_bf16(qf1, kc[2 * t + 1], sacc[t], 0, 0, 0);
    }
    // scale + causal mask + row max (in-lane over t, then DPP over 16 lanes)
    float mt[4];
    #pragma unroll
    for (int r = 0; r < 4; r++) mt[r] = -3.0e38f;
    #pragma unroll
    for (int t = 0; t < 4; t++) {
      int kvc = kv0 + t * 16 + l16;
      #pragma unroll
      for (int r = 0; r < 4; r++) {
        float s = sacc[t][r] * 0.125f;
        if (kvc > qrow + r) s = -3.0e38f;
        sacc[t][r] = s;
        mt[r] = fmaxf(mt[r], s);
      }
    }
    #pragma unroll
    for (int r = 0; r < 4; r++) {
      float m = mt[r];
      m = fmaxf(m, ror16<1>(m));
      m = fmaxf(m, ror16<2>(m));
      m = fmaxf(m, ror16<4>(m));
      m = fmaxf(m, ror16<8>(m));
      mt[r] = m;
    }
    float alpha[4], rs[4];
    #pragma unroll
    for (int r = 0; r < 4; r++) {
      float mn = fmaxf(m_i[r], mt[r]);
      alpha[r] = __expf(m_i[r] - mn);
      m_i[r] = mn;
      rs[r] = 0.0f;
    }
    #pragma unroll
    for (int t = 0; t < 4; t++)
      #pragma unroll
      for (int r = 0; r < 4; r++) {
        float p = __expf(sacc[t][r] - m_i[r]);
        sacc[t][r] = p;
        rs[r] += p;
      }
    #pragma unroll
    for (int r = 0; r < 4; r++) {
      float s = rs[r];
      s += ror16<1>(s);
      s += ror16<2>(s);
      s += ror16<4>(s);
      s += ror16<8>(s);
      l_i[r] = l_i[r] * alpha[r] + s;
    }
    #pragma unroll
    for (int t = 0; t < 4; t++)
      #pragma unroll
      for (int r = 0; r < 4; r++) ao[t][r] *= alpha[r];

    // P: C-layout -> A-layout via per-wave LDS strip
    #pragma unroll
    for (int t = 0; t < 4; t++)
      #pragma unroll
      for (int r = 0; r < 4; r++)
        pw[(quad * 4 + r) * PLD + t * 16 + l16] = f2bf(sacc[t][r]);
    __asm__ volatile("s_waitcnt lgkmcnt(0)" ::: "memory");
    bf16x8 pf0 = *(const bf16x8*)(pw + l16 * PLD + quad * 8);
    bf16x8 pf1 = *(const bf16x8*)(pw + l16 * PLD + 32 + quad * 8);

    // O += P @ V (V frags loaded well before)
    #pragma unroll
    for (int t = 0; t < 4; t++) {
      ao[t] = __builtin_amdgcn_mfma_f32_16x16x32_bf16(pf0, vf[2 * t], ao[t], 0, 0, 0);
      ao[t] = __builtin_amdgcn_mfma_f32_16x16x32_bf16(pf1, vf[2 * t + 1], ao[t], 0, 0, 0);
    }
  };

  bf16x8 ka[8], kb[8];
  loadK(ka, 0);
  for (int it = 0; it < ntiles;) {
    step(ka, kb, it);
    if (++it == ntiles) break;
    step(kb, ka, it);
    if (++it == ntiles) break;
  }

  float inv[4];
  #pragma unroll
  for (int r = 0; r < 4; r++) inv[r] = 1.0f / l_i[r];
  #pragma unroll
  for (int t = 0; t < 4; t++)
    #pragma unroll
    for (int r = 0; r < 4; r++)
      Omat[(rowbase + qrow + r) * (long)D_MODEL + hd0 + t * 16 + l16] =
          f2bf(ao[t][r] * inv[r]);
}

// ---------------- fused residual add (x + partial0 + partial1) + layernorm ----------------
__global__ __launch_bounds__(256) void k_add_ln(
    const float* __restrict__ A, const float* __restrict__ R1,
    const float* __restrict__ R2,
    const float* __restrict__ g, const float* __restrict__ be,
    float* __restrict__ Y, unsigned short* __restrict__ Ybf) {
  __shared__ float sb[4], ssb[4];
  int tid = threadIdx.x;
  long base = (long)blockIdx.x * D_MODEL + tid * 4;
  float4 a  = *(const float4*)(A + base);
  float4 r1 = *(const float4*)(R1 + base);
  float4 r2 = *(const float4*)(R2 + base);
  float v0 = a.x + r1.x + r2.x, v1 = a.y + r1.y + r2.y;
  float v2 = a.z + r1.z + r2.z, v3 = a.w + r1.w + r2.w;
  float s  = v0 + v1 + v2 + v3;
  float ss = v0 * v0 + v1 * v1 + v2 * v2 + v3 * v3;
  #pragma unroll
  for (int o = 32; o >= 1; o >>= 1) {
    s  += __shfl_xor(s, o, 64);
    ss += __shfl_xor(ss, o, 64);
  }
  int wave = tid >> 6;
  if ((tid & 63) == 0) { sb[wave] = s; ssb[wave] = ss; }
  __syncthreads();
  s  = sb[0] + sb[1] + sb[2] + sb[3];
  ss = ssb[0] + ssb[1] + ssb[2] + ssb[3];
  float mu  = s * (1.0f / 1024.0f);
  float var = ss * (1.0f / 1024.0f) - mu * mu;
  float rstd = rsqrtf(var + 1e-6f);
  float4 gv  = *(const float4*)(g + tid * 4);
  float4 bev = *(const float4*)(be + tid * 4);
  float o0 = (v0 - mu) * rstd * gv.x + bev.x;
  float o1 = (v1 - mu) * rstd * gv.y + bev.y;
  float o2 = (v2 - mu) * rstd * gv.z + bev.z;
  float o3 = (v3 - mu) * rstd * gv.w + bev.w;
  if (Y) *(float4*)(Y + base) = make_float4(o0, o1, o2, o3);
  if (Ybf) {
    ushort4 u;
    u.x = f2bf(o0); u.y = f2bf(o1); u.z = f2bf(o2); u.w = f2bf(o3);
    *(ushort4*)(Ybf + base) = u;
  }
}

extern "C" void kernel_launch(void* const* d_in, const int* in_sizes, int n_in,
                              void* d_out, int out_size, void* d_ws, size_t ws_size,
                              hipStream_t stream) {
  (void)in_sizes; (void)n_in; (void)out_size; (void)ws_size;
  const float* x   = (const float*)d_in[0];
  const float* Wq  = (const float*)d_in[1];
  const float* bq  = (const float*)d_in[2];
  const float* Wk  = (const float*)d_in[3];
  const float* bk  = (const float*)d_in[4];
  const float* Wv  = (const float*)d_in[5];
  const float* bv  = (const float*)d_in[6];
  const float* Wo  = (const float*)d_in[7];
  const float* bo  = (const float*)d_in[8];
  const float* g1  = (const float*)d_in[9];
  const float* b1  = (const float*)d_in[10];
  const float* Wup = (const float*)d_in[11];
  const float* bup = (const float*)d_in[12];
  const float* Wdn = (const float*)d_in[13];
  const float* bdn = (const float*)d_in[14];
  const float* g2  = (const float*)d_in[15];
  const float* b2  = (const float*)d_in[16];
  float* out = (float*)d_out;

  char* ws = (char*)d_ws;
  size_t off = 0;
  auto alloc = [&](size_t bytes) {
    char* p = ws + off;
    off = (off + bytes + 255) & ~(size_t)255;
    return p;
  };
  unsigned short* x_bf   = (unsigned short*)alloc((size_t)NROWS * D_MODEL * 2);
  unsigned short* WqkvT  = (unsigned short*)alloc((size_t)QKV_LD * D_MODEL * 2);
  unsigned short* WoT    = (unsigned short*)alloc((size_t)D_MODEL * D_MODEL * 2);
  unsigned short* WupT   = (unsigned short*)alloc((size_t)D_FFN * D_MODEL * 2);
  unsigned short* WdnT   = (unsigned short*)alloc((size_t)D_MODEL * D_FFN * 2);
  float*          bqkv   = (float*)alloc((size_t)QKV_LD * 4);
  unsigned short* qkv_bf = (unsigned short*)alloc((size_t)NROWS * QKV_LD * 2);
  unsigned short* Vt     = (unsigned short*)alloc((size_t)D_MODEL * NROWS * 2);
  unsigned short* mid_bf = (unsigned short*)alloc((size_t)NROWS * D_MODEL * 2);
  float*          x1f    = (float*)alloc((size_t)NROWS * D_MODEL * 4);
  unsigned short* x1bf   = (unsigned short*)alloc((size_t)NROWS * D_MODEL * 2);
  float*          part   = (float*)alloc((size_t)2 * NROWS * D_MODEL * 4);  // split-K partials
  unsigned short* h_bf   = (unsigned short*)alloc((size_t)NROWS * D_FFN * 2);
  float*          part1  = part + (size_t)NROWS * D_MODEL;

  k_f32_to_bf16<<<4096, 256, 0, stream>>>(x, x_bf, (long)NROWS * D_MODEL);
  k_transpose_qkv<<<dim3(32, 32, 3), 256, 0, stream>>>(Wq, Wk, Wv, WqkvT);
  k_transpose_bf16<<<dim3(32, 32), 256, 0, stream>>>(Wo, WoT, D_MODEL, D_MODEL);
  k_transpose_bf16<<<dim3(128, 32), 256, 0, stream>>>(Wup, WupT, D_MODEL, D_FFN);
  k_transpose_bf16<<<dim3(32, 128), 256, 0, stream>>>(Wdn, WdnT, D_FFN, D_MODEL);
  k_pack_bias<<<12, 256, 0, stream>>>(bq, bk, bv, bqkv);

  // QKV projection (merged): [4096][3072]
  k_gemm<<<dim3(32, 24), 256, 0, stream>>>(x_bf, WqkvT, bqkv, qkv_bf,
                                           NROWS, QKV_LD, D_MODEL, 0);
  k_transpose_v<<<dim3(64, 16), 256, 0, stream>>>(qkv_bf, Vt);

  k_attn<<<2048, 128, 0, stream>>>(qkv_bf, Vt, mid_bf);

  // attention out-proj, split-K=2 -> f32 partials
  k_gemm<<<dim3(32, 8, 2), 256, 0, stream>>>(mid_bf, WoT, bo, part,
                                             NROWS, D_MODEL, D_MODEL, 1);
  k_add_ln<<<4096, 256, 0, stream>>>(x, part, part1, g1, b1, x1f, x1bf);

  // FFN up (relu, bf16 out)
  k_gemm<<<dim3(32, 32), 256, 0, stream>>>(x1bf, WupT, bup, h_bf,
                                           NROWS, D_FFN, D_MODEL, 2);
  // FFN down, split-K=2 -> f32 partials
  k_gemm<<<dim3(32, 8, 2), 256, 0, stream>>>(h_bf, WdnT, bdn, part,
                                             NROWS, D_MODEL, D_FFN, 1);
  k_add_ln<<<4096, 256, 0, stream>>>(x1f, part, part1, g2, b2, out, nullptr);
}

// Round 5
// 478.891 us; speedup vs baseline: 1.2404x; 1.0105x over previous
//
#include <hip/hip_runtime.h>

#define D_MODEL 1024
#define D_FFN   4096
#define SEQ     2048
#define NROWS   4096   // B*S
#define QKV_LD  3072

typedef __bf16 bf16x8 __attribute__((ext_vector_type(8)));
typedef float  floatx4 __attribute__((ext_vector_type(4)));

__device__ __forceinline__ unsigned short f2bf(float f) {
  unsigned int u = __float_as_uint(f);
  u += 0x7FFFu + ((u >> 16) & 1u);   // RNE
  return (unsigned short)(u >> 16);
}

// DPP row_ror<N> within 16-lane rows (VALU-speed cross-lane; no LDS pipe)
template <int C>
__device__ __forceinline__ float ror16(float x) {
  return __int_as_float(
      __builtin_amdgcn_mov_dpp(__float_as_int(x), 0x120 | C, 0xf, 0xf, true));
}

// async global->LDS, 16B per lane. lds ptr must be wave-uniform; lane i lands at +i*16B.
__device__ __forceinline__ void async16(const unsigned short* g, unsigned short* l) {
  __builtin_amdgcn_global_load_lds(
      (const __attribute__((address_space(1))) unsigned int*)g,
      (__attribute__((address_space(3))) unsigned int*)l, 16, 0, 0);
}

// ---------------- fp32 -> bf16 elementwise ----------------
__global__ __launch_bounds__(256) void k_f32_to_bf16(
    const float* __restrict__ in, unsigned short* __restrict__ outp, long n) {
  long i = ((long)blockIdx.x * 256 + threadIdx.x) * 4;
  if (i >= n) return;
  float4 v = *(const float4*)(in + i);
  ushort4 o;
  o.x = f2bf(v.x); o.y = f2bf(v.y); o.z = f2bf(v.z); o.w = f2bf(v.w);
  *(ushort4*)(outp + i) = o;
}

// ------------- transpose+convert: W[R][C] f32 -> WT[C][R] bf16 -------------
__global__ __launch_bounds__(256) void k_transpose_bf16(
    const float* __restrict__ W, unsigned short* __restrict__ WT, int R, int C) {
  __shared__ float tile[32][33];
  int tx = threadIdx.x & 31, ty = threadIdx.x >> 5;
  long bx = (long)blockIdx.x * 32;
  long by = (long)blockIdx.y * 32;
  #pragma unroll
  for (int j = 0; j < 4; j++)
    tile[ty + j * 8][tx] = W[(by + ty + j * 8) * C + bx + tx];
  __syncthreads();
  #pragma unroll
  for (int j = 0; j < 4; j++)
    WT[(bx + ty + j * 8) * R + by + tx] = f2bf(tile[tx][ty + j * 8]);
}

// ------------- QKV weight transposes fused (z selects Wq/Wk/Wv) -------------
__global__ __launch_bounds__(256) void k_transpose_qkv(
    const float* __restrict__ Wq, const float* __restrict__ Wk,
    const float* __restrict__ Wv, unsigned short* __restrict__ WT) {
  __shared__ float tile[32][33];
  int z = blockIdx.z;
  const float* W = (z == 0) ? Wq : (z == 1) ? Wk : Wv;
  unsigned short* dst = WT + (size_t)z * D_MODEL * D_MODEL;
  int tx = threadIdx.x & 31, ty = threadIdx.x >> 5;
  long bx = (long)blockIdx.x * 32;
  long by = (long)blockIdx.y * 32;
  #pragma unroll
  for (int j = 0; j < 4; j++)
    tile[ty + j * 8][tx] = W[(by + ty + j * 8) * D_MODEL + bx + tx];
  __syncthreads();
  #pragma unroll
  for (int j = 0; j < 4; j++)
    dst[(bx + ty + j * 8) * D_MODEL + by + tx] = f2bf(tile[tx][ty + j * 8]);
}

__global__ __launch_bounds__(256) void k_pack_bias(
    const float* __restrict__ bq, const float* __restrict__ bk,
    const float* __restrict__ bv, float* __restrict__ dst) {
  int i = blockIdx.x * 256 + threadIdx.x;
  if (i >= 3072) return;
  float v = (i < 1024) ? bq[i] : (i < 2048) ? bk[i - 1024] : bv[i - 2048];
  dst[i] = v;
}

// ------------- V^T: QKV[:, 2048+d] -> Vt[d][row]  (bf16) -------------
__global__ __launch_bounds__(256) void k_transpose_v(
    const unsigned short* __restrict__ QKV, unsigned short* __restrict__ Vt) {
  __shared__ unsigned short tile[64][72];
  int r0 = blockIdx.x * 64;
  int c0 = blockIdx.y * 64;
  int tx = threadIdx.x & 15, ty = threadIdx.x >> 4;
  #pragma unroll
  for (int j = 0; j < 4; j++) {
    int r = ty + j * 16;
    *(ushort4*)&tile[r][tx * 4] =
        *(const ushort4*)(QKV + (long)(r0 + r) * QKV_LD + 2048 + c0 + tx * 4);
  }
  __syncthreads();
  #pragma unroll
  for (int j = 0; j < 4; j++) {
    int d = ty + j * 16;
    ushort4 o;
    o.x = tile[tx * 4 + 0][d];
    o.y = tile[tx * 4 + 1][d];
    o.z = tile[tx * 4 + 2][d];
    o.w = tile[tx * 4 + 3][d];
    *(ushort4*)(Vt + (long)(c0 + d) * NROWS + r0 + tx * 4) = o;
  }
}

// ---------------- m97-style bf16 MFMA GEMM, optional split-K over gridDim.z ----
__global__ __launch_bounds__(256) void k_gemm(
    const unsigned short* __restrict__ A,
    const unsigned short* __restrict__ Bt,
    const float* __restrict__ bias,
    void* __restrict__ Cp, int M, int N, int K, int flags) {
  __shared__ unsigned short As[128 * 32];
  __shared__ unsigned short Bs[128 * 32];
  int tid = threadIdx.x, lane = tid & 63, wave = tid >> 6;
  int quad = lane >> 4, l16 = lane & 15;
  int wm = (wave & 1) * 64, wn = (wave >> 1) * 64;
  long bm = (long)blockIdx.x * 128;
  long bn = (long)blockIdx.y * 128;
  int nz = gridDim.z, z = blockIdx.z;
  int Ks = K / nz;
  long zb = (long)z * Ks;

  const floatx4 fz = {0.f, 0.f, 0.f, 0.f};
  floatx4 acc[4][4];
  #pragma unroll
  for (int i = 0; i < 4; i++)
    #pragma unroll
    for (int j = 0; j < 4; j++) acc[i][j] = fz;

  const unsigned short* Ag = A + (bm + wave * 16 + (lane >> 2)) * (long)K + zb + (lane & 3) * 8;
  const unsigned short* Bg = Bt + (bn + wave * 16 + (lane >> 2)) * (long)K + zb + (lane & 3) * 8;
  unsigned short* Asw = As + wave * 16 * 32;
  unsigned short* Bsw = Bs + wave * 16 * 32;

  for (int k0 = 0; k0 < Ks; k0 += 32) {
    async16(Ag + k0, Asw);
    async16(Ag + (long)64 * K + k0, Asw + 64 * 32);
    async16(Bg + k0, Bsw);
    async16(Bg + (long)64 * K + k0, Bsw + 64 * 32);
    __syncthreads();
    bf16x8 af[4], bfr[4];
    #pragma unroll
    for (int i = 0; i < 4; i++)
      af[i] = *(const bf16x8*)(As + (wm + i * 16 + l16) * 32 + quad * 8);
    #pragma unroll
    for (int j = 0; j < 4; j++)
      bfr[j] = *(const bf16x8*)(Bs + (wn + j * 16 + l16) * 32 + quad * 8);
    #pragma unroll
    for (int i = 0; i < 4; i++)
      #pragma unroll
      for (int j = 0; j < 4; j++)
        acc[i][j] = __builtin_amdgcn_mfma_f32_16x16x32_bf16(af[i], bfr[j], acc[i][j], 0, 0, 0);
    __syncthreads();
  }

  bool f32out = (flags & 1) != 0;
  bool relu   = (flags & 2) != 0;
  float* outf = (float*)Cp + (size_t)z * M * (size_t)N;
  #pragma unroll
  for (int j = 0; j < 4; j++) {
    long col = bn + wn + j * 16 + l16;
    float bvv = (z == 0) ? bias[col] : 0.0f;
    #pragma unroll
    for (int i = 0; i < 4; i++) {
      long row = bm + wm + i * 16 + quad * 4;
      #pragma unroll
      for (int r = 0; r < 4; r++) {
        float v = acc[i][j][r] + bvv;
        if (relu) v = fmaxf(v, 0.0f);
        if (f32out) outf[(row + r) * (long)N + col] = v;
        else        ((unsigned short*)Cp)[(row + r) * (long)N + col] = f2bf(v);
      }
    }
  }
}

// ---------------- flash attention (causal) ----------------
// VALU-diet softmax: exp2-based, group max (one DPP chain), row-sums via MFMA
// (P @ ones), truncating bf16 P-store. Uniform waves: each wave runs strip-pair
// (31-qp, qp) = exactly 33 kv-tiles -> all 512 blocks have identical duration.
#define PLD 72
__global__ __launch_bounds__(256) void k_attn(
    const unsigned short* __restrict__ QKV,
    const unsigned short* __restrict__ Vt,
    unsigned short* __restrict__ Omat) {
  __shared__ unsigned short Ps[4][16 * PLD];
  int tid = threadIdx.x;
  int lane = tid & 63, wave = tid >> 6;
  int quad = lane >> 4, l16 = lane & 15;
  int z = blockIdx.x;
  int bh = z & 31;             // (b,h)
  int qp = z >> 5;             // 0..15: qt pair (31-qp, qp)
  int b = bh >> 4, h = bh & 15;
  long rowbase = (long)b * SEQ;
  int hd0 = h * 64;
  unsigned short* pw = &Ps[wave][0];
  const float SCL = 0.18033688f;   // 0.125 * log2(e)
  const floatx4 fz = {0.f, 0.f, 0.f, 0.f};

  bf16x8 ones;
  #pragma unroll
  for (int i = 0; i < 8; i++) ones[i] = (__bf16)1.0f;

  #pragma unroll
  for (int phase = 0; phase < 2; phase++) {
    int qt = phase ? qp : (31 - qp);
    int q0w = qt * 64 + wave * 16;
    int qrow = q0w + quad * 4;
    int ntiles = qt + 1;

    bf16x8 qf0, qf1;
    {
      const unsigned short* qp_ =
          QKV + (rowbase + q0w + l16) * (long)QKV_LD + hd0 + quad * 8;
      qf0 = *(const bf16x8*)(qp_);
      qf1 = *(const bf16x8*)(qp_ + 32);
    }

    floatx4 ao[4], aol;
    #pragma unroll
    for (int t = 0; t < 4; t++) ao[t] = fz;
    aol = fz;
    float m_i[4];
    #pragma unroll
    for (int r = 0; r < 4; r++) m_i[r] = -3.0e38f;

    auto loadK = [&](bf16x8 (&dst)[8], int kv0) {
      const unsigned short* kp =
          QKV + (rowbase + kv0 + l16) * (long)QKV_LD + 1024 + hd0 + quad * 8;
      #pragma unroll
      for (int t = 0; t < 4; t++) {
        dst[2 * t]     = *(const bf16x8*)(kp + (long)t * 16 * QKV_LD);
        dst[2 * t + 1] = *(const bf16x8*)(kp + (long)t * 16 * QKV_LD + 32);
      }
    };

    auto step = [&](bf16x8 (&kc)[8], bf16x8 (&kn)[8], int it, bool maskt, bool pre) {
      int kv0 = it << 6;
      // V frags first (PV's waitcnt then leaves the K prefetch in flight)
      bf16x8 vf[8];
      {
        const unsigned short* vp =
            Vt + (long)(hd0 + l16) * NROWS + rowbase + kv0 + quad * 8;
        #pragma unroll
        for (int t = 0; t < 4; t++) {
          vf[2 * t]     = *(const bf16x8*)(vp + (long)t * 16 * NROWS);
          vf[2 * t + 1] = *(const bf16x8*)(vp + (long)t * 16 * NROWS + 32);
        }
      }
      if (pre) loadK(kn, kv0 + 64);

      // S = Q @ K^T
      floatx4 sacc[4];
      #pragma unroll
      for (int t = 0; t < 4; t++) {
        sacc[t] = __builtin_amdgcn_mfma_f32_16x16x32_bf16(qf0, kc[2 * t], fz, 0, 0, 0);
        sacc[t] = __builtin_amdgcn_mfma_f32_16x16x32_bf16(qf1, kc[2 * t + 1], sacc[t], 0, 0, 0);
      }

      // scale (exp2 domain) + causal mask (diagonal tile only)
      if (maskt) {
        #pragma unroll
        for (int t = 0; t < 4; t++) {
          int kvc = kv0 + t * 16 + l16;
          #pragma unroll
          for (int r = 0; r < 4; r++) {
            float s = sacc[t][r] * SCL;
            sacc[t][r] = (kvc > qrow + r) ? -1.0e30f : s;
          }
        }
      } else {
        #pragma unroll
        for (int t = 0; t < 4; t++)
          #pragma unroll
          for (int r = 0; r < 4; r++) sacc[t][r] *= SCL;
      }

      // group max over the quad's 16x4 block: in-lane tree + one DPP chain
      float Mg = sacc[0][0];
      #pragma unroll
      for (int t = 0; t < 4; t++)
        #pragma unroll
        for (int r = 0; r < 4; r++) Mg = fmaxf(Mg, sacc[t][r]);
      Mg = fmaxf(Mg, ror16<1>(Mg));
      Mg = fmaxf(Mg, ror16<2>(Mg));
      Mg = fmaxf(Mg, ror16<4>(Mg));
      Mg = fmaxf(Mg, ror16<8>(Mg));

      float alpha[4];
      #pragma unroll
      for (int r = 0; r < 4; r++) {
        float mn = fmaxf(m_i[r], Mg);
        alpha[r] = __builtin_amdgcn_exp2f(m_i[r] - mn);
        m_i[r] = mn;
      }

      // p = exp2(s - m), truncating bf16 store into per-wave P strip
      #pragma unroll
      for (int t = 0; t < 4; t++)
        #pragma unroll
        for (int r = 0; r < 4; r++) {
          float p = __builtin_amdgcn_exp2f(sacc[t][r] - m_i[r]);
          pw[(quad * 4 + r) * PLD + t * 16 + l16] =
              (unsigned short)(__float_as_uint(p) >> 16);
        }

      // rescale running O and l accumulators
      #pragma unroll
      for (int t = 0; t < 4; t++)
        #pragma unroll
        for (int r = 0; r < 4; r++) ao[t][r] *= alpha[r];
      #pragma unroll
      for (int r = 0; r < 4; r++) aol[r] *= alpha[r];

      __asm__ volatile("s_waitcnt lgkmcnt(0)" ::: "memory");
      bf16x8 pf0 = *(const bf16x8*)(pw + l16 * PLD + quad * 8);
      bf16x8 pf1 = *(const bf16x8*)(pw + l16 * PLD + 32 + quad * 8);

      // O += P @ V ; l += P @ ones (row sums via MFMA, no DPP chain)
      #pragma unroll
      for (int t = 0; t < 4; t++) {
        ao[t] = __builtin_amdgcn_mfma_f32_16x16x32_bf16(pf0, vf[2 * t], ao[t], 0, 0, 0);
        ao[t] = __builtin_amdgcn_mfma_f32_16x16x32_bf16(pf1, vf[2 * t + 1], ao[t], 0, 0, 0);
      }
      aol = __builtin_amdgcn_mfma_f32_16x16x32_bf16(pf0, ones, aol, 0, 0, 0);
      aol = __builtin_amdgcn_mfma_f32_16x16x32_bf16(pf1, ones, aol, 0, 0, 0);
    };

    bf16x8 ka[8], kb[8];
    loadK(ka, 0);
    int it = 0;
    while (true) {
      if (it == ntiles - 1) { step(ka, kb, it, true, false); break; }
      step(ka, kb, it, false, true);
      ++it;
      if (it == ntiles - 1) { step(kb, ka, it, true, false); break; }
      step(kb, ka, it, false, true);
      ++it;
    }

    float inv[4];
    #pragma unroll
    for (int r = 0; r < 4; r++) inv[r] = 1.0f / aol[r];
    #pragma unroll
    for (int t = 0; t < 4; t++)
      #pragma unroll
      for (int r = 0; r < 4; r++)
        Omat[(rowbase + qrow + r) * (long)D_MODEL + hd0 + t * 16 + l16] =
            f2bf(ao[t][r] * inv[r]);
  }
}

// ---------------- fused residual add (x + partial0 + partial1) + layernorm ----------------
__global__ __launch_bounds__(256) void k_add_ln(
    const float* __restrict__ A, const float* __restrict__ R1,
    const float* __restrict__ R2,
    const float* __restrict__ g, const float* __restrict__ be,
    float* __restrict__ Y, unsigned short* __restrict__ Ybf) {
  __shared__ float sb[4], ssb[4];
  int tid = threadIdx.x;
  long base = (long)blockIdx.x * D_MODEL + tid * 4;
  float4 a  = *(const float4*)(A + base);
  float4 r1 = *(const float4*)(R1 + base);
  float4 r2 = *(const float4*)(R2 + base);
  float v0 = a.x + r1.x + r2.x, v1 = a.y + r1.y + r2.y;
  float v2 = a.z + r1.z + r2.z, v3 = a.w + r1.w + r2.w;
  float s  = v0 + v1 + v2 + v3;
  float ss = v0 * v0 + v1 * v1 + v2 * v2 + v3 * v3;
  #pragma unroll
  for (int o = 32; o >= 1; o >>= 1) {
    s  += __shfl_xor(s, o, 64);
    ss += __shfl_xor(ss, o, 64);
  }
  int wave = tid >> 6;
  if ((tid & 63) == 0) { sb[wave] = s; ssb[wave] = ss; }
  __syncthreads();
  s  = sb[0] + sb[1] + sb[2] + sb[3];
  ss = ssb[0] + ssb[1] + ssb[2] + ssb[3];
  float mu  = s * (1.0f / 1024.0f);
  float var = ss * (1.0f / 1024.0f) - mu * mu;
  float rstd = rsqrtf(var + 1e-6f);
  float4 gv  = *(const float4*)(g + tid * 4);
  float4 bev = *(const float4*)(be + tid * 4);
  float o0 = (v0 - mu) * rstd * gv.x + bev.x;
  float o1 = (v1 - mu) * rstd * gv.y + bev.y;
  float o2 = (v2 - mu) * rstd * gv.z + bev.z;
  float o3 = (v3 - mu) * rstd * gv.w + bev.w;
  if (Y) *(float4*)(Y + base) = make_float4(o0, o1, o2, o3);
  if (Ybf) {
    ushort4 u;
    u.x = f2bf(o0); u.y = f2bf(o1); u.z = f2bf(o2); u.w = f2bf(o3);
    *(ushort4*)(Ybf + base) = u;
  }
}

extern "C" void kernel_launch(void* const* d_in, const int* in_sizes, int n_in,
                              void* d_out, int out_size, void* d_ws, size_t ws_size,
                              hipStream_t stream) {
  (void)in_sizes; (void)n_in; (void)out_size; (void)ws_size;
  const float* x   = (const float*)d_in[0];
  const float* Wq  = (const float*)d_in[1];
  const float* bq  = (const float*)d_in[2];
  const float* Wk  = (const float*)d_in[3];
  const float* bk  = (const float*)d_in[4];
  const float* Wv  = (const float*)d_in[5];
  const float* bv  = (const float*)d_in[6];
  const float* Wo  = (const float*)d_in[7];
  const float* bo  = (const float*)d_in[8];
  const float* g1  = (const float*)d_in[9];
  const float* b1  = (const float*)d_in[10];
  const float* Wup = (const float*)d_in[11];
  const float* bup = (const float*)d_in[12];
  const float* Wdn = (const float*)d_in[13];
  const float* bdn = (const float*)d_in[14];
  const float* g2  = (const float*)d_in[15];
  const float* b2  = (const float*)d_in[16];
  float* out = (float*)d_out;

  char* ws = (char*)d_ws;
  size_t off = 0;
  auto alloc = [&](size_t bytes) {
    char* p = ws + off;
    off = (off + bytes + 255) & ~(size_t)255;
    return p;
  };
  unsigned short* x_bf   = (unsigned short*)alloc((size_t)NROWS * D_MODEL * 2);
  unsigned short* WqkvT  = (unsigned short*)alloc((size_t)QKV_LD * D_MODEL * 2);
  unsigned short* WoT    = (unsigned short*)alloc((size_t)D_MODEL * D_MODEL * 2);
  unsigned short* WupT   = (unsigned short*)alloc((size_t)D_FFN * D_MODEL * 2);
  unsigned short* WdnT   = (unsigned short*)alloc((size_t)D_MODEL * D_FFN * 2);
  float*          bqkv   = (float*)alloc((size_t)QKV_LD * 4);
  unsigned short* qkv_bf = (unsigned short*)alloc((size_t)NROWS * QKV_LD * 2);
  unsigned short* Vt     = (unsigned short*)alloc((size_t)D_MODEL * NROWS * 2);
  unsigned short* mid_bf = (unsigned short*)alloc((size_t)NROWS * D_MODEL * 2);
  float*          x1f    = (float*)alloc((size_t)NROWS * D_MODEL * 4);
  unsigned short* x1bf   = (unsigned short*)alloc((size_t)NROWS * D_MODEL * 2);
  float*          part   = (float*)alloc((size_t)2 * NROWS * D_MODEL * 4);
  unsigned short* h_bf   = (unsigned short*)alloc((size_t)NROWS * D_FFN * 2);
  float*          part1  = part + (size_t)NROWS * D_MODEL;

  k_f32_to_bf16<<<4096, 256, 0, stream>>>(x, x_bf, (long)NROWS * D_MODEL);
  k_transpose_qkv<<<dim3(32, 32, 3), 256, 0, stream>>>(Wq, Wk, Wv, WqkvT);
  k_transpose_bf16<<<dim3(32, 32), 256, 0, stream>>>(Wo, WoT, D_MODEL, D_MODEL);
  k_transpose_bf16<<<dim3(128, 32), 256, 0, stream>>>(Wup, WupT, D_MODEL, D_FFN);
  k_transpose_bf16<<<dim3(32, 128), 256, 0, stream>>>(Wdn, WdnT, D_FFN, D_MODEL);
  k_pack_bias<<<12, 256, 0, stream>>>(bq, bk, bv, bqkv);

  k_gemm<<<dim3(32, 24), 256, 0, stream>>>(x_bf, WqkvT, bqkv, qkv_bf,
                                           NROWS, QKV_LD, D_MODEL, 0);
  k_transpose_v<<<dim3(64, 16), 256, 0, stream>>>(qkv_bf, Vt);

  k_attn<<<512, 256, 0, stream>>>(qkv_bf, Vt, mid_bf);

  k_gemm<<<dim3(32, 8, 2), 256, 0, stream>>>(mid_bf, WoT, bo, part,
                                             NROWS, D_MODEL, D_MODEL, 1);
  k_add_ln<<<4096, 256, 0, stream>>>(x, part, part1, g1, b1, x1f, x1bf);

  k_gemm<<<dim3(32, 32), 256, 0, stream>>>(x1bf, WupT, bup, h_bf,
                                           NROWS, D_FFN, D_MODEL, 2);
  k_gemm<<<dim3(32, 8, 2), 256, 0, stream>>>(h_bf, WdnT, bdn, part,
                                             NROWS, D_MODEL, D_FFN, 1);
  k_add_ln<<<4096, 256, 0, stream>>>(x1f, part, part1, g2, b2, out, nullptr);
}

// Round 6
// 406.945 us; speedup vs baseline: 1.4597x; 1.1768x over previous
//
#include <hip/hip_runtime.h>

#define D_MODEL 1024
#define D_FFN   4096
#define SEQ     2048
#define NROWS   4096   // B*S
#define QKV_LD  3072

typedef __bf16 bf16x8 __attribute__((ext_vector_type(8)));
typedef float  floatx4 __attribute__((ext_vector_type(4)));

__device__ __forceinline__ unsigned short f2bf(float f) {
  unsigned int u = __float_as_uint(f);
  u += 0x7FFFu + ((u >> 16) & 1u);   // RNE
  return (unsigned short)(u >> 16);
}

// DPP row_ror<N> within 16-lane rows (VALU-speed cross-lane; no LDS pipe)
template <int C>
__device__ __forceinline__ float ror16(float x) {
  return __int_as_float(
      __builtin_amdgcn_mov_dpp(__float_as_int(x), 0x120 | C, 0xf, 0xf, true));
}

// async global->LDS, 16B per lane. LDS dest = wave-uniform base + lane*16.
__device__ __forceinline__ void async16(const unsigned short* g, unsigned short* l) {
  __builtin_amdgcn_global_load_lds(
      (const __attribute__((address_space(1))) unsigned int*)g,
      (__attribute__((address_space(3))) unsigned int*)l, 16, 0, 0);
}

// ---------------- fp32 -> bf16 elementwise ----------------
__global__ __launch_bounds__(256) void k_f32_to_bf16(
    const float* __restrict__ in, unsigned short* __restrict__ outp, long n) {
  long i = ((long)blockIdx.x * 256 + threadIdx.x) * 4;
  if (i >= n) return;
  float4 v = *(const float4*)(in + i);
  ushort4 o;
  o.x = f2bf(v.x); o.y = f2bf(v.y); o.z = f2bf(v.z); o.w = f2bf(v.w);
  *(ushort4*)(outp + i) = o;
}

// ------------- transpose+convert: W[R][C] f32 -> WT[C][R] bf16 -------------
__global__ __launch_bounds__(256) void k_transpose_bf16(
    const float* __restrict__ W, unsigned short* __restrict__ WT, int R, int C) {
  __shared__ float tile[32][33];
  int tx = threadIdx.x & 31, ty = threadIdx.x >> 5;
  long bx = (long)blockIdx.x * 32;
  long by = (long)blockIdx.y * 32;
  #pragma unroll
  for (int j = 0; j < 4; j++)
    tile[ty + j * 8][tx] = W[(by + ty + j * 8) * C + bx + tx];
  __syncthreads();
  #pragma unroll
  for (int j = 0; j < 4; j++)
    WT[(bx + ty + j * 8) * R + by + tx] = f2bf(tile[tx][ty + j * 8]);
}

// ------------- QKV weight transposes fused (z selects Wq/Wk/Wv) -------------
__global__ __launch_bounds__(256) void k_transpose_qkv(
    const float* __restrict__ Wq, const float* __restrict__ Wk,
    const float* __restrict__ Wv, unsigned short* __restrict__ WT) {
  __shared__ float tile[32][33];
  int z = blockIdx.z;
  const float* W = (z == 0) ? Wq : (z == 1) ? Wk : Wv;
  unsigned short* dst = WT + (size_t)z * D_MODEL * D_MODEL;
  int tx = threadIdx.x & 31, ty = threadIdx.x >> 5;
  long bx = (long)blockIdx.x * 32;
  long by = (long)blockIdx.y * 32;
  #pragma unroll
  for (int j = 0; j < 4; j++)
    tile[ty + j * 8][tx] = W[(by + ty + j * 8) * D_MODEL + bx + tx];
  __syncthreads();
  #pragma unroll
  for (int j = 0; j < 4; j++)
    dst[(bx + ty + j * 8) * D_MODEL + by + tx] = f2bf(tile[tx][ty + j * 8]);
}

__global__ __launch_bounds__(256) void k_pack_bias(
    const float* __restrict__ bq, const float* __restrict__ bk,
    const float* __restrict__ bv, float* __restrict__ dst) {
  int i = blockIdx.x * 256 + threadIdx.x;
  if (i >= 3072) return;
  float v = (i < 1024) ? bq[i] : (i < 2048) ? bk[i - 1024] : bv[i - 2048];
  dst[i] = v;
}

// ------------- V^T: QKV[:, 2048+d] -> Vt[d][row]  (bf16) -------------
__global__ __launch_bounds__(256) void k_transpose_v(
    const unsigned short* __restrict__ QKV, unsigned short* __restrict__ Vt) {
  __shared__ unsigned short tile[64][72];
  int r0 = blockIdx.x * 64;
  int c0 = blockIdx.y * 64;
  int tx = threadIdx.x & 15, ty = threadIdx.x >> 4;
  #pragma unroll
  for (int j = 0; j < 4; j++) {
    int r = ty + j * 16;
    *(ushort4*)&tile[r][tx * 4] =
        *(const ushort4*)(QKV + (long)(r0 + r) * QKV_LD + 2048 + c0 + tx * 4);
  }
  __syncthreads();
  #pragma unroll
  for (int j = 0; j < 4; j++) {
    int d = ty + j * 16;
    ushort4 o;
    o.x = tile[tx * 4 + 0][d];
    o.y = tile[tx * 4 + 1][d];
    o.z = tile[tx * 4 + 2][d];
    o.w = tile[tx * 4 + 3][d];
    *(ushort4*)(Vt + (long)(c0 + d) * NROWS + r0 + tx * 4) = o;
  }
}

// ---------------- m97-style bf16 MFMA GEMM, optional split-K over gridDim.z ----
__global__ __launch_bounds__(256) void k_gemm(
    const unsigned short* __restrict__ A,
    const unsigned short* __restrict__ Bt,
    const float* __restrict__ bias,
    void* __restrict__ Cp, int M, int N, int K, int flags) {
  __shared__ unsigned short As[128 * 32];
  __shared__ unsigned short Bs[128 * 32];
  int tid = threadIdx.x, lane = tid & 63, wave = tid >> 6;
  int quad = lane >> 4, l16 = lane & 15;
  int wm = (wave & 1) * 64, wn = (wave >> 1) * 64;
  long bm = (long)blockIdx.x * 128;
  long bn = (long)blockIdx.y * 128;
  int nz = gridDim.z, z = blockIdx.z;
  int Ks = K / nz;
  long zb = (long)z * Ks;

  const floatx4 fz = {0.f, 0.f, 0.f, 0.f};
  floatx4 acc[4][4];
  #pragma unroll
  for (int i = 0; i < 4; i++)
    #pragma unroll
    for (int j = 0; j < 4; j++) acc[i][j] = fz;

  const unsigned short* Ag = A + (bm + wave * 16 + (lane >> 2)) * (long)K + zb + (lane & 3) * 8;
  const unsigned short* Bg = Bt + (bn + wave * 16 + (lane >> 2)) * (long)K + zb + (lane & 3) * 8;
  unsigned short* Asw = As + wave * 16 * 32;
  unsigned short* Bsw = Bs + wave * 16 * 32;

  for (int k0 = 0; k0 < Ks; k0 += 32) {
    async16(Ag + k0, Asw);
    async16(Ag + (long)64 * K + k0, Asw + 64 * 32);
    async16(Bg + k0, Bsw);
    async16(Bg + (long)64 * K + k0, Bsw + 64 * 32);
    __syncthreads();
    bf16x8 af[4], bfr[4];
    #pragma unroll
    for (int i = 0; i < 4; i++)
      af[i] = *(const bf16x8*)(As + (wm + i * 16 + l16) * 32 + quad * 8);
    #pragma unroll
    for (int j = 0; j < 4; j++)
      bfr[j] = *(const bf16x8*)(Bs + (wn + j * 16 + l16) * 32 + quad * 8);
    #pragma unroll
    for (int i = 0; i < 4; i++)
      #pragma unroll
      for (int j = 0; j < 4; j++)
        acc[i][j] = __builtin_amdgcn_mfma_f32_16x16x32_bf16(af[i], bfr[j], acc[i][j], 0, 0, 0);
    __syncthreads();
  }

  bool f32out = (flags & 1) != 0;
  bool relu   = (flags & 2) != 0;
  float* outf = (float*)Cp + (size_t)z * M * (size_t)N;
  #pragma unroll
  for (int j = 0; j < 4; j++) {
    long col = bn + wn + j * 16 + l16;
    float bvv = (z == 0) ? bias[col] : 0.0f;
    #pragma unroll
    for (int i = 0; i < 4; i++) {
      long row = bm + wm + i * 16 + quad * 4;
      #pragma unroll
      for (int r = 0; r < 4; r++) {
        float v = acc[i][j][r] + bvv;
        if (relu) v = fmaxf(v, 0.0f);
        if (f32out) outf[(row + r) * (long)N + col] = v;
        else        ((unsigned short*)Cp)[(row + r) * (long)N + col] = f2bf(v);
      }
    }
  }
}

// ---------------- flash attention (causal), LDS-staged K/V ----------------
// K/V tiles staged ONCE per block via global_load_lds (coalesced 1KB/issue),
// shared by 4 waves -> 4x fewer cache-line requests than per-wave gathers.
// XOR chunk swizzle (chunk c at position c^(row&7)) makes all ds_read_b128
// frag reads 2-way on banks (free) without padding (global_load_lds forbids it).
// Uniform schedule: block=(bh,qp), phases qt=31-qp then qt=qp, 33 tiles/block.
#define PLD 72
__global__ __launch_bounds__(256) void k_attn(
    const unsigned short* __restrict__ QKV,
    const unsigned short* __restrict__ Vt,
    unsigned short* __restrict__ Omat) {
  __shared__ unsigned short Ks[64 * 64];   // [kv][d], chunk-swizzled
  __shared__ unsigned short Vs[64 * 64];   // [d][kv], chunk-swizzled
  __shared__ unsigned short Ps[4][16 * PLD];
  int tid = threadIdx.x;
  int lane = tid & 63, wave = tid >> 6;
  int quad = lane >> 4, l16 = lane & 15;
  int z = blockIdx.x;
  int bh = z & 31;
  int qp = z >> 5;                 // 0..15
  int b = bh >> 4, h = bh & 15;
  long rowbase = (long)b * SEQ;
  int hd0 = h * 64;
  unsigned short* pw = &Ps[wave][0];
  const float SCL = 0.18033688f;   // 0.125 * log2(e)
  const floatx4 fz = {0.f, 0.f, 0.f, 0.f};

  // staging lane mapping: call j covers tile-rows 8j..8j+7; lane i -> row 8j+(i>>3),
  // LDS chunk position i&7 holds global chunk c = (i&7) ^ (row&7).
  int r_in = lane >> 3;
  int cpos = lane & 7;

  bf16x8 ones;
  #pragma unroll
  for (int i = 0; i < 8; i++) ones[i] = (__bf16)1.0f;

  #pragma unroll
  for (int phase = 0; phase < 2; phase++) {
    int qt = phase ? qp : (31 - qp);
    int q0w = qt * 64 + wave * 16;
    int qrow = q0w + quad * 4;
    int ntiles = qt + 1;

    bf16x8 qf0, qf1;
    {
      const unsigned short* qp_ =
          QKV + (rowbase + q0w + l16) * (long)QKV_LD + hd0 + quad * 8;
      qf0 = *(const bf16x8*)(qp_);
      qf1 = *(const bf16x8*)(qp_ + 32);
    }

    floatx4 ao[4], aol;
    #pragma unroll
    for (int t = 0; t < 4; t++) ao[t] = fz;
    aol = fz;
    float m_i[4];
    #pragma unroll
    for (int r = 0; r < 4; r++) m_i[r] = -3.0e38f;

    for (int it = 0; it < ntiles; it++) {
      int kv0 = it << 6;
      // ---- stage K and V tiles (each wave stages 2 of 8 chunks of each) ----
      #pragma unroll
      for (int jj = 0; jj < 2; jj++) {
        int j = wave * 2 + jj;           // 0..7
        int r = j * 8 + r_in;            // row in tile
        int c = cpos ^ (r & 7);          // global 16B-chunk index
        const unsigned short* gk =
            QKV + (rowbase + kv0 + r) * (long)QKV_LD + 1024 + hd0 + c * 8;
        async16(gk, Ks + j * 512);
        const unsigned short* gv =
            Vt + (long)(hd0 + r) * NROWS + rowbase + kv0 + c * 8;
        async16(gv, Vs + j * 512);
      }
      __syncthreads();   // drains vmcnt (staging complete)

      // ---- S = Q @ K^T ----
      floatx4 sacc[4];
      #pragma unroll
      for (int t = 0; t < 4; t++) {
        int row = t * 16 + l16;
        int sw = row & 7;
        bf16x8 kf0 = *(const bf16x8*)(Ks + row * 64 + (quad ^ sw) * 8);
        bf16x8 kf1 = *(const bf16x8*)(Ks + row * 64 + ((quad + 4) ^ sw) * 8);
        sacc[t] = __builtin_amdgcn_mfma_f32_16x16x32_bf16(qf0, kf0, fz, 0, 0, 0);
        sacc[t] = __builtin_amdgcn_mfma_f32_16x16x32_bf16(qf1, kf1, sacc[t], 0, 0, 0);
      }

      // ---- scale + causal mask (diagonal tile only) ----
      bool maskt = (it == ntiles - 1);
      if (maskt) {
        #pragma unroll
        for (int t = 0; t < 4; t++) {
          int kvc = kv0 + t * 16 + l16;
          #pragma unroll
          for (int r = 0; r < 4; r++) {
            float s = sacc[t][r] * SCL;
            sacc[t][r] = (kvc > qrow + r) ? -1.0e30f : s;
          }
        }
      } else {
        #pragma unroll
        for (int t = 0; t < 4; t++)
          #pragma unroll
          for (int r = 0; r < 4; r++) sacc[t][r] *= SCL;
      }

      // ---- group max (quad's 16x4 block): in-lane tree + one DPP chain ----
      float Mg = sacc[0][0];
      #pragma unroll
      for (int t = 0; t < 4; t++)
        #pragma unroll
        for (int r = 0; r < 4; r++) Mg = fmaxf(Mg, sacc[t][r]);
      Mg = fmaxf(Mg, ror16<1>(Mg));
      Mg = fmaxf(Mg, ror16<2>(Mg));
      Mg = fmaxf(Mg, ror16<4>(Mg));
      Mg = fmaxf(Mg, ror16<8>(Mg));

      float alpha[4];
      #pragma unroll
      for (int r = 0; r < 4; r++) {
        float mn = fmaxf(m_i[r], Mg);
        alpha[r] = __builtin_amdgcn_exp2f(m_i[r] - mn);
        m_i[r] = mn;
      }

      // ---- p = exp2(s - m), truncating bf16 store into per-wave P strip ----
      #pragma unroll
      for (int t = 0; t < 4; t++)
        #pragma unroll
        for (int r = 0; r < 4; r++) {
          float p = __builtin_amdgcn_exp2f(sacc[t][r] - m_i[r]);
          pw[(quad * 4 + r) * PLD + t * 16 + l16] =
              (unsigned short)(__float_as_uint(p) >> 16);
        }

      // rescale running O and l accumulators
      #pragma unroll
      for (int t = 0; t < 4; t++)
        #pragma unroll
        for (int r = 0; r < 4; r++) ao[t][r] *= alpha[r];
      #pragma unroll
      for (int r = 0; r < 4; r++) aol[r] *= alpha[r];

      __asm__ volatile("s_waitcnt lgkmcnt(0)" ::: "memory");
      bf16x8 pf0 = *(const bf16x8*)(pw + l16 * PLD + quad * 8);
      bf16x8 pf1 = *(const bf16x8*)(pw + l16 * PLD + 32 + quad * 8);

      // ---- O += P @ V ; l += P @ ones ----
      #pragma unroll
      for (int t = 0; t < 4; t++) {
        int row = t * 16 + l16;
        int sw = row & 7;
        bf16x8 vf0 = *(const bf16x8*)(Vs + row * 64 + (quad ^ sw) * 8);
        bf16x8 vf1 = *(const bf16x8*)(Vs + row * 64 + ((quad + 4) ^ sw) * 8);
        ao[t] = __builtin_amdgcn_mfma_f32_16x16x32_bf16(pf0, vf0, ao[t], 0, 0, 0);
        ao[t] = __builtin_amdgcn_mfma_f32_16x16x32_bf16(pf1, vf1, ao[t], 0, 0, 0);
      }
      aol = __builtin_amdgcn_mfma_f32_16x16x32_bf16(pf0, ones, aol, 0, 0, 0);
      aol = __builtin_amdgcn_mfma_f32_16x16x32_bf16(pf1, ones, aol, 0, 0, 0);

      __syncthreads();   // protect Ks/Vs for next tile's staging
    }

    float inv[4];
    #pragma unroll
    for (int r = 0; r < 4; r++) inv[r] = 1.0f / aol[r];
    #pragma unroll
    for (int t = 0; t < 4; t++)
      #pragma unroll
      for (int r = 0; r < 4; r++)
        Omat[(rowbase + qrow + r) * (long)D_MODEL + hd0 + t * 16 + l16] =
            f2bf(ao[t][r] * inv[r]);
  }
}

// ---------------- fused residual add (x + partial0 + partial1) + layernorm ----------------
__global__ __launch_bounds__(256) void k_add_ln(
    const float* __restrict__ A, const float* __restrict__ R1,
    const float* __restrict__ R2,
    const float* __restrict__ g, const float* __restrict__ be,
    float* __restrict__ Y, unsigned short* __restrict__ Ybf) {
  __shared__ float sb[4], ssb[4];
  int tid = threadIdx.x;
  long base = (long)blockIdx.x * D_MODEL + tid * 4;
  float4 a  = *(const float4*)(A + base);
  float4 r1 = *(const float4*)(R1 + base);
  float4 r2 = *(const float4*)(R2 + base);
  float v0 = a.x + r1.x + r2.x, v1 = a.y + r1.y + r2.y;
  float v2 = a.z + r1.z + r2.z, v3 = a.w + r1.w + r2.w;
  float s  = v0 + v1 + v2 + v3;
  float ss = v0 * v0 + v1 * v1 + v2 * v2 + v3 * v3;
  #pragma unroll
  for (int o = 32; o >= 1; o >>= 1) {
    s  += __shfl_xor(s, o, 64);
    ss += __shfl_xor(ss, o, 64);
  }
  int wave = tid >> 6;
  if ((tid & 63) == 0) { sb[wave] = s; ssb[wave] = ss; }
  __syncthreads();
  s  = sb[0] + sb[1] + sb[2] + sb[3];
  ss = ssb[0] + ssb[1] + ssb[2] + ssb[3];
  float mu  = s * (1.0f / 1024.0f);
  float var = ss * (1.0f / 1024.0f) - mu * mu;
  float rstd = rsqrtf(var + 1e-6f);
  float4 gv  = *(const float4*)(g + tid * 4);
  float4 bev = *(const float4*)(be + tid * 4);
  float o0 = (v0 - mu) * rstd * gv.x + bev.x;
  float o1 = (v1 - mu) * rstd * gv.y + bev.y;
  float o2 = (v2 - mu) * rstd * gv.z + bev.z;
  float o3 = (v3 - mu) * rstd * gv.w + bev.w;
  if (Y) *(float4*)(Y + base) = make_float4(o0, o1, o2, o3);
  if (Ybf) {
    ushort4 u;
    u.x = f2bf(o0); u.y = f2bf(o1); u.z = f2bf(o2); u.w = f2bf(o3);
    *(ushort4*)(Ybf + base) = u;
  }
}

extern "C" void kernel_launch(void* const* d_in, const int* in_sizes, int n_in,
                              void* d_out, int out_size, void* d_ws, size_t ws_size,
                              hipStream_t stream) {
  (void)in_sizes; (void)n_in; (void)out_size; (void)ws_size;
  const float* x   = (const float*)d_in[0];
  const float* Wq  = (const float*)d_in[1];
  const float* bq  = (const float*)d_in[2];
  const float* Wk  = (const float*)d_in[3];
  const float* bk  = (const float*)d_in[4];
  const float* Wv  = (const float*)d_in[5];
  const float* bv  = (const float*)d_in[6];
  const float* Wo  = (const float*)d_in[7];
  const float* bo  = (const float*)d_in[8];
  const float* g1  = (const float*)d_in[9];
  const float* b1  = (const float*)d_in[10];
  const float* Wup = (const float*)d_in[11];
  const float* bup = (const float*)d_in[12];
  const float* Wdn = (const float*)d_in[13];
  const float* bdn = (const float*)d_in[14];
  const float* g2  = (const float*)d_in[15];
  const float* b2  = (const float*)d_in[16];
  float* out = (float*)d_out;

  char* ws = (char*)d_ws;
  size_t off = 0;
  auto alloc = [&](size_t bytes) {
    char* p = ws + off;
    off = (off + bytes + 255) & ~(size_t)255;
    return p;
  };
  unsigned short* x_bf   = (unsigned short*)alloc((size_t)NROWS * D_MODEL * 2);
  unsigned short* WqkvT  = (unsigned short*)alloc((size_t)QKV_LD * D_MODEL * 2);
  unsigned short* WoT    = (unsigned short*)alloc((size_t)D_MODEL * D_MODEL * 2);
  unsigned short* WupT   = (unsigned short*)alloc((size_t)D_FFN * D_MODEL * 2);
  unsigned short* WdnT   = (unsigned short*)alloc((size_t)D_MODEL * D_FFN * 2);
  float*          bqkv   = (float*)alloc((size_t)QKV_LD * 4);
  unsigned short* qkv_bf = (unsigned short*)alloc((size_t)NROWS * QKV_LD * 2);
  unsigned short* Vt     = (unsigned short*)alloc((size_t)D_MODEL * NROWS * 2);
  unsigned short* mid_bf = (unsigned short*)alloc((size_t)NROWS * D_MODEL * 2);
  float*          x1f    = (float*)alloc((size_t)NROWS * D_MODEL * 4);
  unsigned short* x1bf   = (unsigned short*)alloc((size_t)NROWS * D_MODEL * 2);
  float*          part   = (float*)alloc((size_t)2 * NROWS * D_MODEL * 4);
  unsigned short* h_bf   = (unsigned short*)alloc((size_t)NROWS * D_FFN * 2);
  float*          part1  = part + (size_t)NROWS * D_MODEL;

  k_f32_to_bf16<<<4096, 256, 0, stream>>>(x, x_bf, (long)NROWS * D_MODEL);
  k_transpose_qkv<<<dim3(32, 32, 3), 256, 0, stream>>>(Wq, Wk, Wv, WqkvT);
  k_transpose_bf16<<<dim3(32, 32), 256, 0, stream>>>(Wo, WoT, D_MODEL, D_MODEL);
  k_transpose_bf16<<<dim3(128, 32), 256, 0, stream>>>(Wup, WupT, D_MODEL, D_FFN);
  k_transpose_bf16<<<dim3(32, 128), 256, 0, stream>>>(Wdn, WdnT, D_FFN, D_MODEL);
  k_pack_bias<<<12, 256, 0, stream>>>(bq, bk, bv, bqkv);

  k_gemm<<<dim3(32, 24), 256, 0, stream>>>(x_bf, WqkvT, bqkv, qkv_bf,
                                           NROWS, QKV_LD, D_MODEL, 0);
  k_transpose_v<<<dim3(64, 16), 256, 0, stream>>>(qkv_bf, Vt);

  k_attn<<<512, 256, 0, stream>>>(qkv_bf, Vt, mid_bf);

  k_gemm<<<dim3(32, 8, 2), 256, 0, stream>>>(mid_bf, WoT, bo, part,
                                             NROWS, D_MODEL, D_MODEL, 1);
  k_add_ln<<<4096, 256, 0, stream>>>(x, part, part1, g1, b1, x1f, x1bf);

  k_gemm<<<dim3(32, 32), 256, 0, stream>>>(x1bf, WupT, bup, h_bf,
                                           NROWS, D_FFN, D_MODEL, 2);
  k_gemm<<<dim3(32, 8, 2), 256, 0, stream>>>(h_bf, WdnT, bdn, part,
                                             NROWS, D_MODEL, D_FFN, 1);
  k_add_ln<<<4096, 256, 0, stream>>>(x1f, part, part1, g2, b2, out, nullptr);
}

// Round 7
// 395.083 us; speedup vs baseline: 1.5035x; 1.0300x over previous
//
#include <hip/hip_runtime.h>

#define D_MODEL 1024
#define D_FFN   4096
#define SEQ     2048
#define NROWS   4096   // B*S
#define QKV_LD  3072
#define BKG     64     // GEMM K-tile

typedef __bf16 bf16x8 __attribute__((ext_vector_type(8)));
typedef float  floatx4 __attribute__((ext_vector_type(4)));

__device__ __forceinline__ unsigned short f2bf(float f) {
  unsigned int u = __float_as_uint(f);
  u += 0x7FFFu + ((u >> 16) & 1u);   // RNE
  return (unsigned short)(u >> 16);
}

// DPP row_ror<N> within 16-lane rows (VALU-speed cross-lane; no LDS pipe)
template <int C>
__device__ __forceinline__ float ror16(float x) {
  return __int_as_float(
      __builtin_amdgcn_mov_dpp(__float_as_int(x), 0x120 | C, 0xf, 0xf, true));
}

// async global->LDS, 16B per lane. LDS dest = wave-uniform base + lane*16.
__device__ __forceinline__ void async16(const unsigned short* g, unsigned short* l) {
  __builtin_amdgcn_global_load_lds(
      (const __attribute__((address_space(1))) unsigned int*)g,
      (__attribute__((address_space(3))) unsigned int*)l, 16, 0, 0);
}

// ---------------- fp32 -> bf16 elementwise ----------------
__global__ __launch_bounds__(256) void k_f32_to_bf16(
    const float* __restrict__ in, unsigned short* __restrict__ outp, long n) {
  long i = ((long)blockIdx.x * 256 + threadIdx.x) * 4;
  if (i >= n) return;
  float4 v = *(const float4*)(in + i);
  ushort4 o;
  o.x = f2bf(v.x); o.y = f2bf(v.y); o.z = f2bf(v.z); o.w = f2bf(v.w);
  *(ushort4*)(outp + i) = o;
}

// ------------- transpose+convert: W[R][C] f32 -> WT[C][R] bf16 -------------
__global__ __launch_bounds__(256) void k_transpose_bf16(
    const float* __restrict__ W, unsigned short* __restrict__ WT, int R, int C) {
  __shared__ float tile[32][33];
  int tx = threadIdx.x & 31, ty = threadIdx.x >> 5;
  long bx = (long)blockIdx.x * 32;
  long by = (long)blockIdx.y * 32;
  #pragma unroll
  for (int j = 0; j < 4; j++)
    tile[ty + j * 8][tx] = W[(by + ty + j * 8) * C + bx + tx];
  __syncthreads();
  #pragma unroll
  for (int j = 0; j < 4; j++)
    WT[(bx + ty + j * 8) * R + by + tx] = f2bf(tile[tx][ty + j * 8]);
}

// ------------- 1024x1024 weight transposes fused (z: Wq,Wk,Wv -> WqkvT; Wo -> WoT) ------
__global__ __launch_bounds__(256) void k_transpose_sq(
    const float* __restrict__ Wq, const float* __restrict__ Wk,
    const float* __restrict__ Wv, const float* __restrict__ Wo,
    unsigned short* __restrict__ WqkvT, unsigned short* __restrict__ WoT) {
  __shared__ float tile[32][33];
  int z = blockIdx.z;
  const float* W = (z == 0) ? Wq : (z == 1) ? Wk : (z == 2) ? Wv : Wo;
  unsigned short* dst = (z < 3) ? (WqkvT + (size_t)z * D_MODEL * D_MODEL) : WoT;
  int tx = threadIdx.x & 31, ty = threadIdx.x >> 5;
  long bx = (long)blockIdx.x * 32;
  long by = (long)blockIdx.y * 32;
  #pragma unroll
  for (int j = 0; j < 4; j++)
    tile[ty + j * 8][tx] = W[(by + ty + j * 8) * D_MODEL + bx + tx];
  __syncthreads();
  #pragma unroll
  for (int j = 0; j < 4; j++)
    dst[(bx + ty + j * 8) * D_MODEL + by + tx] = f2bf(tile[tx][ty + j * 8]);
}

__global__ __launch_bounds__(256) void k_pack_bias(
    const float* __restrict__ bq, const float* __restrict__ bk,
    const float* __restrict__ bv, float* __restrict__ dst) {
  int i = blockIdx.x * 256 + threadIdx.x;
  if (i >= 3072) return;
  float v = (i < 1024) ? bq[i] : (i < 2048) ? bk[i - 1024] : bv[i - 2048];
  dst[i] = v;
}

// ------------- V^T: QKV[:, 2048+d] -> Vt[d][row]  (bf16) -------------
__global__ __launch_bounds__(256) void k_transpose_v(
    const unsigned short* __restrict__ QKV, unsigned short* __restrict__ Vt) {
  __shared__ unsigned short tile[64][72];
  int r0 = blockIdx.x * 64;
  int c0 = blockIdx.y * 64;
  int tx = threadIdx.x & 15, ty = threadIdx.x >> 4;
  #pragma unroll
  for (int j = 0; j < 4; j++) {
    int r = ty + j * 16;
    *(ushort4*)&tile[r][tx * 4] =
        *(const ushort4*)(QKV + (long)(r0 + r) * QKV_LD + 2048 + c0 + tx * 4);
  }
  __syncthreads();
  #pragma unroll
  for (int j = 0; j < 4; j++) {
    int d = ty + j * 16;
    ushort4 o;
    o.x = tile[tx * 4 + 0][d];
    o.y = tile[tx * 4 + 1][d];
    o.z = tile[tx * 4 + 2][d];
    o.w = tile[tx * 4 + 3][d];
    *(ushort4*)(Vt + (long)(c0 + d) * NROWS + r0 + tx * 4) = o;
  }
}

// ---------------- bf16 MFMA GEMM: BK=64, XOR-swizzled LDS, split-K via gridDim.z ----
// C[M][N] = A[M][K] @ Bt[N][K]^T + bias. 128x128 tile. flags: bit0 f32out, bit1 relu.
// LDS rows are 128B (64 u16); 16B chunk c of row r stored at position c^(r&7):
// all ds_read_b128 frag reads land 2-way on banks (free, m136), staging stays
// global_load_lds-legal (wave-uniform base + lane*16).
__global__ __launch_bounds__(256) void k_gemm(
    const unsigned short* __restrict__ A,
    const unsigned short* __restrict__ Bt,
    const float* __restrict__ bias,
    void* __restrict__ Cp, int M, int N, int K, int flags) {
  __shared__ unsigned short As[128 * BKG];
  __shared__ unsigned short Bs[128 * BKG];
  int tid = threadIdx.x, lane = tid & 63, wave = tid >> 6;
  int quad = lane >> 4, l16 = lane & 15;
  int wm = (wave & 1) * 64, wn = (wave >> 1) * 64;
  long bm = (long)blockIdx.x * 128;
  long bn = (long)blockIdx.y * 128;
  int nz = gridDim.z, z = blockIdx.z;
  int Ks = K / nz;
  long zb = (long)z * Ks;

  const floatx4 fz = {0.f, 0.f, 0.f, 0.f};
  floatx4 acc[4][4];
  #pragma unroll
  for (int i = 0; i < 4; i++)
    #pragma unroll
    for (int j = 0; j < 4; j++) acc[i][j] = fz;

  // staging mapping: call j covers rows j*32 + wave*8 .. +7; lane -> row wave*8+(lane>>3),
  // LDS chunk position lane&7 holds global chunk (lane&7)^(row&7) = (lane&7)^(lane>>3).
  int srow = lane >> 3;
  int sc = (lane & 7) ^ srow;
  const unsigned short* Ag = A + (bm + wave * 8 + srow) * (long)K + zb + sc * 8;
  const unsigned short* Bg = Bt + (bn + wave * 8 + srow) * (long)K + zb + sc * 8;
  unsigned short* Asw = As + wave * 8 * BKG;
  unsigned short* Bsw = Bs + wave * 8 * BKG;

  for (int k0 = 0; k0 < Ks; k0 += BKG) {
    #pragma unroll
    for (int j = 0; j < 4; j++) {
      async16(Ag + (long)j * 32 * K + k0, Asw + j * 32 * BKG);
      async16(Bg + (long)j * 32 * K + k0, Bsw + j * 32 * BKG);
    }
    __syncthreads();
    bf16x8 af[4][2], bfr[4][2];
    #pragma unroll
    for (int i = 0; i < 4; i++) {
      int r = wm + i * 16 + l16;
      int sw = r & 7;
      af[i][0] = *(const bf16x8*)(As + r * BKG + (quad ^ sw) * 8);
      af[i][1] = *(const bf16x8*)(As + r * BKG + ((4 + quad) ^ sw) * 8);
    }
    #pragma unroll
    for (int j = 0; j < 4; j++) {
      int r = wn + j * 16 + l16;
      int sw = r & 7;
      bfr[j][0] = *(const bf16x8*)(Bs + r * BKG + (quad ^ sw) * 8);
      bfr[j][1] = *(const bf16x8*)(Bs + r * BKG + ((4 + quad) ^ sw) * 8);
    }
    #pragma unroll
    for (int h = 0; h < 2; h++)
      #pragma unroll
      for (int i = 0; i < 4; i++)
        #pragma unroll
        for (int j = 0; j < 4; j++)
          acc[i][j] = __builtin_amdgcn_mfma_f32_16x16x32_bf16(af[i][h], bfr[j][h],
                                                             acc[i][j], 0, 0, 0);
    __syncthreads();
  }

  bool f32out = (flags & 1) != 0;
  bool relu   = (flags & 2) != 0;
  float* outf = (float*)Cp + (size_t)z * M * (size_t)N;
  #pragma unroll
  for (int j = 0; j < 4; j++) {
    long col = bn + wn + j * 16 + l16;
    float bvv = (z == 0) ? bias[col] : 0.0f;
    #pragma unroll
    for (int i = 0; i < 4; i++) {
      long row = bm + wm + i * 16 + quad * 4;
      #pragma unroll
      for (int r = 0; r < 4; r++) {
        float v = acc[i][j][r] + bvv;
        if (relu) v = fmaxf(v, 0.0f);
        if (f32out) outf[(row + r) * (long)N + col] = v;
        else        ((unsigned short*)Cp)[(row + r) * (long)N + col] = f2bf(v);
      }
    }
  }
}

// ---------------- flash attention (causal), LDS-staged K/V ----------------
#define PLD 72
__global__ __launch_bounds__(256) void k_attn(
    const unsigned short* __restrict__ QKV,
    const unsigned short* __restrict__ Vt,
    unsigned short* __restrict__ Omat) {
  __shared__ unsigned short Ks[64 * 64];   // [kv][d], chunk-swizzled
  __shared__ unsigned short Vs[64 * 64];   // [d][kv], chunk-swizzled
  __shared__ unsigned short Ps[4][16 * PLD];
  int tid = threadIdx.x;
  int lane = tid & 63, wave = tid >> 6;
  int quad = lane >> 4, l16 = lane & 15;
  int z = blockIdx.x;
  int bh = z & 31;
  int qp = z >> 5;                 // 0..15
  int b = bh >> 4, h = bh & 15;
  long rowbase = (long)b * SEQ;
  int hd0 = h * 64;
  unsigned short* pw = &Ps[wave][0];
  const float SCL = 0.18033688f;   // 0.125 * log2(e)
  const floatx4 fz = {0.f, 0.f, 0.f, 0.f};

  int r_in = lane >> 3;
  int cpos = lane & 7;

  bf16x8 ones;
  #pragma unroll
  for (int i = 0; i < 8; i++) ones[i] = (__bf16)1.0f;

  #pragma unroll
  for (int phase = 0; phase < 2; phase++) {
    int qt = phase ? qp : (31 - qp);
    int q0w = qt * 64 + wave * 16;
    int qrow = q0w + quad * 4;
    int ntiles = qt + 1;

    bf16x8 qf0, qf1;
    {
      const unsigned short* qp_ =
          QKV + (rowbase + q0w + l16) * (long)QKV_LD + hd0 + quad * 8;
      qf0 = *(const bf16x8*)(qp_);
      qf1 = *(const bf16x8*)(qp_ + 32);
    }

    floatx4 ao[4], aol;
    #pragma unroll
    for (int t = 0; t < 4; t++) ao[t] = fz;
    aol = fz;
    float m_i[4];
    #pragma unroll
    for (int r = 0; r < 4; r++) m_i[r] = -3.0e38f;

    for (int it = 0; it < ntiles; it++) {
      int kv0 = it << 6;
      #pragma unroll
      for (int jj = 0; jj < 2; jj++) {
        int j = wave * 2 + jj;
        int r = j * 8 + r_in;
        int c = cpos ^ (r & 7);
        const unsigned short* gk =
            QKV + (rowbase + kv0 + r) * (long)QKV_LD + 1024 + hd0 + c * 8;
        async16(gk, Ks + j * 512);
        const unsigned short* gv =
            Vt + (long)(hd0 + r) * NROWS + rowbase + kv0 + c * 8;
        async16(gv, Vs + j * 512);
      }
      __syncthreads();

      floatx4 sacc[4];
      #pragma unroll
      for (int t = 0; t < 4; t++) {
        int row = t * 16 + l16;
        int sw = row & 7;
        bf16x8 kf0 = *(const bf16x8*)(Ks + row * 64 + (quad ^ sw) * 8);
        bf16x8 kf1 = *(const bf16x8*)(Ks + row * 64 + ((quad + 4) ^ sw) * 8);
        sacc[t] = __builtin_amdgcn_mfma_f32_16x16x32_bf16(qf0, kf0, fz, 0, 0, 0);
        sacc[t] = __builtin_amdgcn_mfma_f32_16x16x32_bf16(qf1, kf1, sacc[t], 0, 0, 0);
      }

      bool maskt = (it == ntiles - 1);
      if (maskt) {
        #pragma unroll
        for (int t = 0; t < 4; t++) {
          int kvc = kv0 + t * 16 + l16;
          #pragma unroll
          for (int r = 0; r < 4; r++) {
            float s = sacc[t][r] * SCL;
            sacc[t][r] = (kvc > qrow + r) ? -1.0e30f : s;
          }
        }
      } else {
        #pragma unroll
        for (int t = 0; t < 4; t++)
          #pragma unroll
          for (int r = 0; r < 4; r++) sacc[t][r] *= SCL;
      }

      float Mg = sacc[0][0];
      #pragma unroll
      for (int t = 0; t < 4; t++)
        #pragma unroll
        for (int r = 0; r < 4; r++) Mg = fmaxf(Mg, sacc[t][r]);
      Mg = fmaxf(Mg, ror16<1>(Mg));
      Mg = fmaxf(Mg, ror16<2>(Mg));
      Mg = fmaxf(Mg, ror16<4>(Mg));
      Mg = fmaxf(Mg, ror16<8>(Mg));

      float alpha[4];
      #pragma unroll
      for (int r = 0; r < 4; r++) {
        float mn = fmaxf(m_i[r], Mg);
        alpha[r] = __builtin_amdgcn_exp2f(m_i[r] - mn);
        m_i[r] = mn;
      }

      #pragma unroll
      for (int t = 0; t < 4; t++)
        #pragma unroll
        for (int r = 0; r < 4; r++) {
          float p = __builtin_amdgcn_exp2f(sacc[t][r] - m_i[r]);
          pw[(quad * 4 + r) * PLD + t * 16 + l16] =
              (unsigned short)(__float_as_uint(p) >> 16);
        }

      #pragma unroll
      for (int t = 0; t < 4; t++)
        #pragma unroll
        for (int r = 0; r < 4; r++) ao[t][r] *= alpha[r];
      #pragma unroll
      for (int r = 0; r < 4; r++) aol[r] *= alpha[r];

      __asm__ volatile("s_waitcnt lgkmcnt(0)" ::: "memory");
      bf16x8 pf0 = *(const bf16x8*)(pw + l16 * PLD + quad * 8);
      bf16x8 pf1 = *(const bf16x8*)(pw + l16 * PLD + 32 + quad * 8);

      #pragma unroll
      for (int t = 0; t < 4; t++) {
        int row = t * 16 + l16;
        int sw = row & 7;
        bf16x8 vf0 = *(const bf16x8*)(Vs + row * 64 + (quad ^ sw) * 8);
        bf16x8 vf1 = *(const bf16x8*)(Vs + row * 64 + ((quad + 4) ^ sw) * 8);
        ao[t] = __builtin_amdgcn_mfma_f32_16x16x32_bf16(pf0, vf0, ao[t], 0, 0, 0);
        ao[t] = __builtin_amdgcn_mfma_f32_16x16x32_bf16(pf1, vf1, ao[t], 0, 0, 0);
      }
      aol = __builtin_amdgcn_mfma_f32_16x16x32_bf16(pf0, ones, aol, 0, 0, 0);
      aol = __builtin_amdgcn_mfma_f32_16x16x32_bf16(pf1, ones, aol, 0, 0, 0);

      __syncthreads();
    }

    float inv[4];
    #pragma unroll
    for (int r = 0; r < 4; r++) inv[r] = 1.0f / aol[r];
    #pragma unroll
    for (int t = 0; t < 4; t++)
      #pragma unroll
      for (int r = 0; r < 4; r++)
        Omat[(rowbase + qrow + r) * (long)D_MODEL + hd0 + t * 16 + l16] =
            f2bf(ao[t][r] * inv[r]);
  }
}

// ---------------- fused residual add (x + partial0 + partial1) + layernorm ----------------
__global__ __launch_bounds__(256) void k_add_ln(
    const float* __restrict__ A, const float* __restrict__ R1,
    const float* __restrict__ R2,
    const float* __restrict__ g, const float* __restrict__ be,
    float* __restrict__ Y, unsigned short* __restrict__ Ybf) {
  __shared__ float sb[4], ssb[4];
  int tid = threadIdx.x;
  long base = (long)blockIdx.x * D_MODEL + tid * 4;
  float4 a  = *(const float4*)(A + base);
  float4 r1 = *(const float4*)(R1 + base);
  float4 r2 = *(const float4*)(R2 + base);
  float v0 = a.x + r1.x + r2.x, v1 = a.y + r1.y + r2.y;
  float v2 = a.z + r1.z + r2.z, v3 = a.w + r1.w + r2.w;
  float s  = v0 + v1 + v2 + v3;
  float ss = v0 * v0 + v1 * v1 + v2 * v2 + v3 * v3;
  #pragma unroll
  for (int o = 32; o >= 1; o >>= 1) {
    s  += __shfl_xor(s, o, 64);
    ss += __shfl_xor(ss, o, 64);
  }
  int wave = tid >> 6;
  if ((tid & 63) == 0) { sb[wave] = s; ssb[wave] = ss; }
  __syncthreads();
  s  = sb[0] + sb[1] + sb[2] + sb[3];
  ss = ssb[0] + ssb[1] + ssb[2] + ssb[3];
  float mu  = s * (1.0f / 1024.0f);
  float var = ss * (1.0f / 1024.0f) - mu * mu;
  float rstd = rsqrtf(var + 1e-6f);
  float4 gv  = *(const float4*)(g + tid * 4);
  float4 bev = *(const float4*)(be + tid * 4);
  float o0 = (v0 - mu) * rstd * gv.x + bev.x;
  float o1 = (v1 - mu) * rstd * gv.y + bev.y;
  float o2 = (v2 - mu) * rstd * gv.z + bev.z;
  float o3 = (v3 - mu) * rstd * gv.w + bev.w;
  if (Y) *(float4*)(Y + base) = make_float4(o0, o1, o2, o3);
  if (Ybf) {
    ushort4 u;
    u.x = f2bf(o0); u.y = f2bf(o1); u.z = f2bf(o2); u.w = f2bf(o3);
    *(ushort4*)(Ybf + base) = u;
  }
}

extern "C" void kernel_launch(void* const* d_in, const int* in_sizes, int n_in,
                              void* d_out, int out_size, void* d_ws, size_t ws_size,
                              hipStream_t stream) {
  (void)in_sizes; (void)n_in; (void)out_size; (void)ws_size;
  const float* x   = (const float*)d_in[0];
  const float* Wq  = (const float*)d_in[1];
  const float* bq  = (const float*)d_in[2];
  const float* Wk  = (const float*)d_in[3];
  const float* bk  = (const float*)d_in[4];
  const float* Wv  = (const float*)d_in[5];
  const float* bv  = (const float*)d_in[6];
  const float* Wo  = (const float*)d_in[7];
  const float* bo  = (const float*)d_in[8];
  const float* g1  = (const float*)d_in[9];
  const float* b1  = (const float*)d_in[10];
  const float* Wup = (const float*)d_in[11];
  const float* bup = (const float*)d_in[12];
  const float* Wdn = (const float*)d_in[13];
  const float* bdn = (const float*)d_in[14];
  const float* g2  = (const float*)d_in[15];
  const float* b2  = (const float*)d_in[16];
  float* out = (float*)d_out;

  char* ws = (char*)d_ws;
  size_t off = 0;
  auto alloc = [&](size_t bytes) {
    char* p = ws + off;
    off = (off + bytes + 255) & ~(size_t)255;
    return p;
  };
  unsigned short* x_bf   = (unsigned short*)alloc((size_t)NROWS * D_MODEL * 2);
  unsigned short* WqkvT  = (unsigned short*)alloc((size_t)QKV_LD * D_MODEL * 2);
  unsigned short* WoT    = (unsigned short*)alloc((size_t)D_MODEL * D_MODEL * 2);
  unsigned short* WupT   = (unsigned short*)alloc((size_t)D_FFN * D_MODEL * 2);
  unsigned short* WdnT   = (unsigned short*)alloc((size_t)D_MODEL * D_FFN * 2);
  float*          bqkv   = (float*)alloc((size_t)QKV_LD * 4);
  unsigned short* qkv_bf = (unsigned short*)alloc((size_t)NROWS * QKV_LD * 2);
  unsigned short* Vt     = (unsigned short*)alloc((size_t)D_MODEL * NROWS * 2);
  unsigned short* mid_bf = (unsigned short*)alloc((size_t)NROWS * D_MODEL * 2);
  float*          x1f    = (float*)alloc((size_t)NROWS * D_MODEL * 4);
  unsigned short* x1bf   = (unsigned short*)alloc((size_t)NROWS * D_MODEL * 2);
  float*          part   = (float*)alloc((size_t)2 * NROWS * D_MODEL * 4);
  unsigned short* h_bf   = (unsigned short*)alloc((size_t)NROWS * D_FFN * 2);
  float*          part1  = part + (size_t)NROWS * D_MODEL;

  k_f32_to_bf16<<<4096, 256, 0, stream>>>(x, x_bf, (long)NROWS * D_MODEL);
  k_transpose_sq<<<dim3(32, 32, 4), 256, 0, stream>>>(Wq, Wk, Wv, Wo, WqkvT, WoT);
  k_transpose_bf16<<<dim3(128, 32), 256, 0, stream>>>(Wup, WupT, D_MODEL, D_FFN);
  k_transpose_bf16<<<dim3(32, 128), 256, 0, stream>>>(Wdn, WdnT, D_FFN, D_MODEL);
  k_pack_bias<<<12, 256, 0, stream>>>(bq, bk, bv, bqkv);

  k_gemm<<<dim3(32, 24), 256, 0, stream>>>(x_bf, WqkvT, bqkv, qkv_bf,
                                           NROWS, QKV_LD, D_MODEL, 0);
  k_transpose_v<<<dim3(64, 16), 256, 0, stream>>>(qkv_bf, Vt);

  k_attn<<<512, 256, 0, stream>>>(qkv_bf, Vt, mid_bf);

  k_gemm<<<dim3(32, 8, 2), 256, 0, stream>>>(mid_bf, WoT, bo, part,
                                             NROWS, D_MODEL, D_MODEL, 1);
  k_add_ln<<<4096, 256, 0, stream>>>(x, part, part1, g1, b1, x1f, x1bf);

  k_gemm<<<dim3(32, 32), 256, 0, stream>>>(x1bf, WupT, bup, h_bf,
                                           NROWS, D_FFN, D_MODEL, 2);
  k_gemm<<<dim3(32, 8, 2), 256, 0, stream>>>(h_bf, WdnT, bdn, part,
                                             NROWS, D_MODEL, D_FFN, 1);
  k_add_ln<<<4096, 256, 0, stream>>>(x1f, part, part1, g2, b2, out, nullptr);
}